// Round 12
// baseline (251.704 us; speedup 1.0000x reference)
//
#include <hip/hip_runtime.h>
#include <stdint.h>

typedef unsigned short u16;
typedef __attribute__((ext_vector_type(8))) short short8;
typedef __attribute__((ext_vector_type(4))) short short4v;
typedef __attribute__((ext_vector_type(4))) float f32x4;

#define NB 2
#define NS 2048
#define ND 1024
#define NH 16
#define NDH 64
#define NBS (NB*NS)   // 4096 rows

__device__ __forceinline__ float bf2f(u16 u) {
  union { uint32_t i; float f; } c; c.i = ((uint32_t)u) << 16; return c.f;
}
__device__ __forceinline__ u16 f2bf(float f) {
  union { float f; uint32_t i; } c; c.f = f;
  uint32_t r = (c.i + 0x7fffu + ((c.i >> 16) & 1u)) >> 16;
  return (u16)r;
}

// ---------------- prep: 4 weight transposes + x->bf16 cast, ONE launch ----------------
__global__ __launch_bounds__(256)
void k_prep(const float* __restrict__ x, u16* __restrict__ xb,
            const float* __restrict__ Wqkv, const float* __restrict__ Wvw,
            const float* __restrict__ WA, const float* __restrict__ WB,
            u16* __restrict__ WqkvT, u16* __restrict__ WvwT,
            u16* __restrict__ WAT, u16* __restrict__ WBT) {
  __shared__ float tile[32][33];
  int id = blockIdx.x;
  if (id >= 12288) {           // cast blocks: 4096 x (256 thr x float4)
    int i = (id - 12288) * 256 + threadIdx.x;
    float4 v = ((const float4*)x)[i];
    uint2 o;
    o.x = (uint32_t)f2bf(v.x) | ((uint32_t)f2bf(v.y) << 16);
    o.y = (uint32_t)f2bf(v.z) | ((uint32_t)f2bf(v.w) << 16);
    ((uint2*)xb)[i] = o;
    return;
  }
  const float* W; u16* WT; int K, N, tid;
  if (id < 3072)      { W = Wqkv; WT = WqkvT; K = 1024; N = 3072; tid = id; }
  else if (id < 4096) { W = Wvw;  WT = WvwT;  K = 1024; N = 1024; tid = id - 3072; }
  else if (id < 8192) { W = WA;   WT = WAT;   K = 1024; N = 4096; tid = id - 4096; }
  else                { W = WB;   WT = WBT;   K = 4096; N = 1024; tid = id - 8192; }
  const int ntx = N >> 5;
  const int n0 = (tid % ntx) << 5, k0 = (tid / ntx) << 5;
  const int tx = threadIdx.x & 31, ty = threadIdx.x >> 5;
  #pragma unroll
  for (int j = 0; j < 4; ++j)
    tile[ty + 8*j][tx] = W[(size_t)(k0 + ty + 8*j) * N + (n0 + tx)];
  __syncthreads();
  const int r = threadIdx.x >> 3;
  const int c4 = (threadIdx.x & 7) * 4;
  short4v o;
  #pragma unroll
  for (int i = 0; i < 4; ++i) o[i] = (short)f2bf(tile[c4 + i][r]);
  *(short4v*)(WT + (size_t)(n0 + r) * K + k0 + c4) = o;
}

// ---------------- transpose V out of qkv: [z][dh] -> Vt[bh][dh][z] (bf16) ----------------
__global__ __launch_bounds__(256)
void k_vt(const u16* __restrict__ qkv, u16* __restrict__ Vt) {
  __shared__ u16 tile[64][72];
  const int zb = blockIdx.x;
  const int bh = blockIdx.y;
  const int b = bh >> 4, h = bh & 15;
  const int t = threadIdx.x;
  const int r = t >> 2, seg = (t & 3) * 16;
  const u16* src = qkv + ((size_t)(b * NS + zb * 64 + r)) * 3072 + 2048 + h * 64 + seg;
  *(short8*)(&tile[r][seg])     = *(const short8*)(src);
  *(short8*)(&tile[r][seg + 8]) = *(const short8*)(src + 8);
  __syncthreads();
  const int dh = t >> 2, zs = (t & 3) * 16;
  short8 o0, o1;
  #pragma unroll
  for (int i = 0; i < 8; ++i) o0[i] = (short)tile[zs + i][dh];
  #pragma unroll
  for (int i = 0; i < 8; ++i) o1[i] = (short)tile[zs + 8 + i][dh];
  u16* dst = Vt + (size_t)(bh * 64 + dh) * NS + zb * 64 + zs;
  *(short8*)(dst)     = o0;
  *(short8*)(dst + 8) = o1;
}

// ---------------- async global->LDS, 16B ----------------
__device__ __forceinline__ void gload_lds16(const void* g, void* l) {
  __builtin_amdgcn_global_load_lds(
      (const __attribute__((address_space(1))) void*)(void*)(uintptr_t)g,
      (__attribute__((address_space(3))) void*)l, 16, 0, 0);
}

// ---------------- 128x128 bf16 MFMA GEMM (m97 structure), split-K capable ----------------
template<bool OUT_BF16, bool RELU>
__global__ __launch_bounds__(256)
void k_gemm_bt(const u16* __restrict__ A, const u16* __restrict__ BT,
               const float* __restrict__ bias, void* __restrict__ C,
               int M, int N, int Kstride, int Klen, size_t zCstride)
{
  __shared__ u16 As[128 * 64];
  __shared__ u16 Bs[128 * 64];
  const int t = threadIdx.x, wave = t >> 6, lane = t & 63;
  const int m0 = blockIdx.y * 128, n0 = blockIdx.x * 128;
  const int wr = wave >> 1, wc = wave & 1;
  const int koff = blockIdx.z * Klen;
  A  += koff;
  BT += koff;

  f32x4 acc[4][4] = {};

  int srow[4], scol[4];
  #pragma unroll
  for (int p = 0; p < 4; ++p) {
    int o = p * 4096 + wave * 1024 + lane * 16;
    int r = o >> 7;
    int cb = o & 127;
    srow[p] = r;
    scol[p] = (cb ^ ((r & 7) << 4)) >> 1;
  }

  const int nkt = Klen >> 6;
  for (int kt = 0; kt < nkt; ++kt) {
    const int k0 = kt << 6;
    #pragma unroll
    for (int p = 0; p < 4; ++p) {
      const u16* srcA = A  + (size_t)(m0 + srow[p]) * Kstride + k0 + scol[p];
      const u16* srcB = BT + (size_t)(n0 + srow[p]) * Kstride + k0 + scol[p];
      gload_lds16(srcA, (char*)As + p * 4096 + wave * 1024);
      gload_lds16(srcB, (char*)Bs + p * 4096 + wave * 1024);
    }
    asm volatile("s_waitcnt vmcnt(0)" ::: "memory");
    __syncthreads();

    #pragma unroll
    for (int kk = 0; kk < 2; ++kk) {
      const int cbase = kk * 64 + ((lane >> 4) << 4);
      short8 af[4], bf[4];
      #pragma unroll
      for (int mi = 0; mi < 4; ++mi) {
        int r = wr * 64 + mi * 16 + (lane & 15);
        af[mi] = *(const short8*)((const char*)As + r * 128 + (cbase ^ ((r & 7) << 4)));
      }
      #pragma unroll
      for (int nj = 0; nj < 4; ++nj) {
        int r = wc * 64 + nj * 16 + (lane & 15);
        bf[nj] = *(const short8*)((const char*)Bs + r * 128 + (cbase ^ ((r & 7) << 4)));
      }
      #pragma unroll
      for (int mi = 0; mi < 4; ++mi)
        #pragma unroll
        for (int nj = 0; nj < 4; ++nj)
          acc[mi][nj] = __builtin_amdgcn_mfma_f32_16x16x32_bf16(af[mi], bf[nj], acc[mi][nj], 0, 0, 0);
    }
    __syncthreads();
  }

  const int lr = (lane >> 4) << 2;
  const int lc = lane & 15;
  #pragma unroll
  for (int nj = 0; nj < 4; ++nj) {
    const int col = n0 + wc * 64 + nj * 16 + lc;
    const float bs = bias ? bias[col] : 0.f;
    #pragma unroll
    for (int mi = 0; mi < 4; ++mi) {
      const int row = m0 + wr * 64 + mi * 16 + lr;
      #pragma unroll
      for (int i = 0; i < 4; ++i) {
        float v = acc[mi][nj][i] + bs;
        if (RELU) v = fmaxf(v, 0.f);
        if (OUT_BF16) ((u16*)C)[blockIdx.z * zCstride + (size_t)(row + i) * N + col] = f2bf(v);
        else          ((float*)C)[blockIdx.z * zCstride + (size_t)(row + i) * N + col] = v;
      }
    }
  }
}

// ---------------- 256x256 8-wave 8-PHASE pipelined GEMM ----------------
__device__ __forceinline__ short8 lds_frag8(const char* base, int row, int kkbyte) {
  return *(const short8*)(base + row * 128 + (kkbyte ^ ((row & 7) << 4)));
}

template<bool OUT_BF16, bool RELU>
__global__ __launch_bounds__(512, 2)
void k_gemm256(const u16* __restrict__ A, const u16* __restrict__ BT,
               const float* __restrict__ bias, void* __restrict__ C,
               int M, int N, int Kstride, int Klen, int nbx,
               size_t zs1, size_t zs2)
{
  extern __shared__ char lds[];
  char* ldsA = lds;
  char* ldsB = lds + 65536;
  const int t = threadIdx.x, wave = t >> 6, lane = t & 63;
  const int lg = lane >> 4, lq = lane & 15;
  const int wr = wave >> 2, wc = wave & 3;

  const int nwg = gridDim.x;
  const int sw = (blockIdx.x & 7) * (nwg >> 3) + (blockIdx.x >> 3);
  const int bx = sw % nbx, by = sw / nbx;
  const int m0 = by * 256, n0 = bx * 256;

  const int koff = blockIdx.z * Klen;
  A  += koff;
  BT += koff;

  const int rr = t >> 3;
  const int scol = ((t & 7) ^ ((t >> 3) & 7)) * 8;
  const u16* Asrc = A  + (size_t)(m0 + rr) * Kstride + scol;
  const u16* Bsrc = BT + (size_t)(n0 + rr) * Kstride + scol;

  const int nkt = Klen >> 6;
  const int nht = nkt << 2;

  f32x4 acc[8][4] = {};
  short8 af[4][2], bf[4][2];

  auto STAGE = [&](int s) {
    if (s < nht) {
      const int tile = s >> 2, part = s & 3, half = part & 1, slot = tile & 1;
      const u16* src = (part < 2 ? Bsrc : Asrc) + (size_t)(half * 128) * Kstride + tile * 64;
      char* d = (part < 2 ? ldsB : ldsA) + slot * 32768 + half * 16384 + wave * 1024;
      gload_lds16(src, d);
      gload_lds16(src + (size_t)64 * Kstride, d + 8192);
    }
  };
  auto RDA = [&](int slot, int mo) {
    const char* base = ldsA + slot * 32768;
    #pragma unroll
    for (int m = 0; m < 4; ++m) {
      const int row = wr * 128 + (mo + m) * 16 + lq;
      af[m][0] = lds_frag8(base, row, lg * 16);
      af[m][1] = lds_frag8(base, row, 64 + lg * 16);
    }
  };
  auto RDB = [&](int slot, int no) {
    const char* base = ldsB + slot * 32768;
    #pragma unroll
    for (int n = 0; n < 2; ++n) {
      const int row = wc * 64 + (no + n) * 16 + lq;
      bf[no + n][0] = lds_frag8(base, row, lg * 16);
      bf[no + n][1] = lds_frag8(base, row, 64 + lg * 16);
    }
  };
  auto MF = [&](int mo, int no) {
    __builtin_amdgcn_s_setprio(1);
    #pragma unroll
    for (int m = 0; m < 4; ++m)
      #pragma unroll
      for (int n = 0; n < 2; ++n) {
        acc[mo + m][no + n] = __builtin_amdgcn_mfma_f32_16x16x32_bf16(af[m][0], bf[no + n][0], acc[mo + m][no + n], 0, 0, 0);
        acc[mo + m][no + n] = __builtin_amdgcn_mfma_f32_16x16x32_bf16(af[m][1], bf[no + n][1], acc[mo + m][no + n], 0, 0, 0);
      }
    __builtin_amdgcn_s_setprio(0);
  };
  #define BAR() asm volatile("s_barrier" ::: "memory")

  #pragma unroll
  for (int s = 0; s < 6; ++s) STAGE(s);
  asm volatile("s_waitcnt vmcnt(4)" ::: "memory");
  __syncthreads();

  const int niter = nkt >> 1;
  #pragma unroll 1
  for (int i = 0; i < niter; ++i) {
    const int bs = 8 * i + 6;
    RDA(0, 0); RDB(0, 0); STAGE(bs + 0);
    BAR(); MF(0, 0); BAR();
    RDB(0, 2); STAGE(bs + 1);
    BAR(); MF(0, 2); BAR();
    RDA(0, 4); STAGE(bs + 2);
    BAR(); MF(4, 0); BAR();
    STAGE(bs + 3);
    if (i == niter - 1) { asm volatile("s_waitcnt vmcnt(0)" ::: "memory"); }
    else                { asm volatile("s_waitcnt vmcnt(4)" ::: "memory"); }
    BAR(); MF(4, 2); BAR();
    RDA(1, 0); RDB(1, 0); STAGE(bs + 4);
    BAR(); MF(0, 0); BAR();
    RDB(1, 2); STAGE(bs + 5);
    BAR(); MF(0, 2); BAR();
    RDA(1, 4); STAGE(bs + 6);
    BAR(); MF(4, 0); BAR();
    STAGE(bs + 7);
    asm volatile("s_waitcnt vmcnt(4)" ::: "memory");
    BAR(); MF(4, 2); BAR();
  }
  #undef BAR

  const size_t zoff = (size_t)(blockIdx.z & 1) * zs1 + (size_t)(blockIdx.z >> 1) * zs2;
  #pragma unroll
  for (int n = 0; n < 4; ++n) {
    const int col = n0 + wc * 64 + n * 16 + lq;
    const float bs = bias ? bias[col] : 0.f;
    #pragma unroll
    for (int m = 0; m < 8; ++m) {
      const int row = m0 + wr * 128 + m * 16 + lg * 4;
      #pragma unroll
      for (int i = 0; i < 4; ++i) {
        float v = acc[m][n][i] + bs;
        if (RELU) v = fmaxf(v, 0.f);
        if (OUT_BF16) ((u16*)C)[zoff + (size_t)(row + i) * N + col] = f2bf(v);
        else          ((float*)C)[zoff + (size_t)(row + i) * N + col] = v;
      }
    }
  }
}

// ---------------- flash attention v8: QBLK=64, 4 waves, grid (32,32) -> 3 blocks/CU ----------------
__global__ __launch_bounds__(256)
void k_flash_attn(const u16* __restrict__ qkv, const u16* __restrict__ Vt,
                  u16* __restrict__ vw)
{
  __shared__ u16 Ks[2][64 * 64];      // 16KB
  __shared__ u16 Vts[2][64 * 64];     // 16KB
  __shared__ u16 P_lds[4][16 * 72];   // 9KB -> 41KB total

  const int qb = 31 - (int)blockIdx.x;   // LPT over 64-row q-blocks
  const int bh = blockIdx.y;
  const int b = bh >> 4, h = bh & 15;
  const int t = threadIdx.x, wave = t >> 6, lane = t & 63;
  const int lg = lane >> 4, lq = lane & 15;

  const int q0w = qb * 64 + wave * 16;

  const float QSC = 0.18033688f;         // 0.125 * log2(e)
  short8 bq[2];
  {
    const u16* qrow = qkv + ((size_t)(b * NS + q0w + lq)) * 3072 + h * 64 + lg * 8;
    short8 r0 = *(const short8*)(qrow);
    short8 r1 = *(const short8*)(qrow + 32);
    union { short8 s; uint32_t u[4]; } o0, o1;
    #pragma unroll
    for (int p = 0; p < 4; ++p) {
      float a0 = bf2f((u16)r0[2*p]) * QSC, a1 = bf2f((u16)r0[2*p+1]) * QSC;
      float c0 = bf2f((u16)r1[2*p]) * QSC, c1 = bf2f((u16)r1[2*p+1]) * QSC;
      asm("v_cvt_pk_bf16_f32 %0, %1, %2" : "=v"(o0.u[p]) : "v"(a0), "v"(a1));
      asm("v_cvt_pk_bf16_f32 %0, %1, %2" : "=v"(o1.u[p]) : "v"(c0), "v"(c1));
    }
    bq[0] = o0.s; bq[1] = o1.s;
  }

  f32x4 o_acc[4] = {};
  float m_run = -1e30f, l_run = 0.f;

  const u16* kbase = qkv + (size_t)b * NS * 3072 + 1024 + h * 64;
  const u16* vtb   = Vt + (size_t)bh * 64 * NS;

  const int so = t * 32;
  const int sr = so >> 7;
  const int cb = so & 127;
  const int swz = (sr & 7) << 4;
  const int sc0 = (cb ^ swz) >> 1;
  const int sc1 = ((cb + 16) ^ swz) >> 1;
  const int npairs = (qb >> 1) + 1;

  short8 rg[8];
  auto LOADP = [&](int z0) {
    const u16* k0 = kbase + (size_t)(z0 + sr) * 3072;
    const u16* k1 = kbase + (size_t)(z0 + 64 + sr) * 3072;
    const u16* v0 = vtb + (size_t)sr * NS + z0;
    rg[0] = *(const short8*)(k0 + sc0);
    rg[1] = *(const short8*)(k0 + sc1);
    rg[2] = *(const short8*)(k1 + sc0);
    rg[3] = *(const short8*)(k1 + sc1);
    rg[4] = *(const short8*)(v0 + sc0);
    rg[5] = *(const short8*)(v0 + sc1);
    rg[6] = *(const short8*)(v0 + 64 + sc0);
    rg[7] = *(const short8*)(v0 + 64 + sc1);
  };

  LOADP(0);

  for (int kp = 0; kp < npairs; ++kp) {
    const int z0 = kp * 128;
    asm volatile("s_waitcnt vmcnt(0)" ::: "memory");
    *(short8*)((char*)Ks[0]  + so)      = rg[0];
    *(short8*)((char*)Ks[0]  + so + 16) = rg[1];
    *(short8*)((char*)Ks[1]  + so)      = rg[2];
    *(short8*)((char*)Ks[1]  + so + 16) = rg[3];
    *(short8*)((char*)Vts[0] + so)      = rg[4];
    *(short8*)((char*)Vts[0] + so + 16) = rg[5];
    *(short8*)((char*)Vts[1] + so)      = rg[6];
    *(short8*)((char*)Vts[1] + so + 16) = rg[7];
    if (kp + 1 < npairs) LOADP(z0 + 128);
    asm volatile("s_waitcnt lgkmcnt(0)" ::: "memory");
    asm volatile("s_barrier" ::: "memory");

    #pragma unroll
    for (int sub = 0; sub < 2; ++sub) {
      const int zz = z0 + (sub << 6);
      if (zz <= q0w + 15) {
        f32x4 s_acc[4];
        __builtin_amdgcn_s_setprio(1);
        #pragma unroll
        for (int kb = 0; kb < 4; ++kb) {
          const int r = kb * 16 + lq;
          const int sw = (r & 7) << 4;
          short8 ak0 = *(const short8*)((const char*)Ks[sub] + r * 128 + ((lg * 16) ^ sw));
          short8 ak1 = *(const short8*)((const char*)Ks[sub] + r * 128 + ((64 + lg * 16) ^ sw));
          f32x4 zr = {0.f, 0.f, 0.f, 0.f};
          zr = __builtin_amdgcn_mfma_f32_16x16x32_bf16(ak0, bq[0], zr, 0, 0, 0);
          s_acc[kb] = __builtin_amdgcn_mfma_f32_16x16x32_bf16(ak1, bq[1], zr, 0, 0, 0);
        }
        __builtin_amdgcn_s_setprio(0);

        short8 vb[4][2];
        #pragma unroll
        for (int nb = 0; nb < 4; ++nb) {
          const int rv = nb * 16 + lq;
          const int swv = (rv & 7) << 4;
          vb[nb][0] = *(const short8*)((const char*)Vts[sub] + rv * 128 + ((lg * 16) ^ swv));
          vb[nb][1] = *(const short8*)((const char*)Vts[sub] + rv * 128 + ((64 + lg * 16) ^ swv));
        }

        float sv[16];
        #pragma unroll
        for (int kb = 0; kb < 4; ++kb)
          #pragma unroll
          for (int i = 0; i < 4; ++i)
            sv[kb * 4 + i] = s_acc[kb][i];

        if (zz + 63 > q0w) {
          #pragma unroll
          for (int kb = 0; kb < 4; ++kb)
            #pragma unroll
            for (int i = 0; i < 4; ++i)
              if (zz + kb * 16 + lg * 4 + i > q0w + lq) sv[kb * 4 + i] = -1e30f;
        }

        float tm = -1e30f;
        #pragma unroll
        for (int j = 0; j < 16; ++j) tm = fmaxf(tm, sv[j]);
        tm = fmaxf(tm, __shfl_xor(tm, 16));
        tm = fmaxf(tm, __shfl_xor(tm, 32));

        if (!__all(tm <= m_run + 11.5415603f)) {
          const float m_new = fmaxf(m_run, tm);
          const float scl = __builtin_amdgcn_exp2f(m_run - m_new);
          float s0 = __shfl(scl, lg * 4 + 0);
          float s1 = __shfl(scl, lg * 4 + 1);
          float s2 = __shfl(scl, lg * 4 + 2);
          float s3 = __shfl(scl, lg * 4 + 3);
          #pragma unroll
          for (int nb = 0; nb < 4; ++nb) {
            o_acc[nb][0] *= s0; o_acc[nb][1] *= s1;
            o_acc[nb][2] *= s2; o_acc[nb][3] *= s3;
          }
          l_run *= scl;
          m_run = m_new;
        }

        float ts = 0.f;
        #pragma unroll
        for (int j = 0; j < 16; ++j) {
          float p = __builtin_amdgcn_exp2f(sv[j] - m_run);
          sv[j] = p; ts += p;
        }
        ts += __shfl_xor(ts, 16);
        ts += __shfl_xor(ts, 32);
        l_run += ts;

        #pragma unroll
        for (int kb = 0; kb < 4; ++kb) {
          uint32_t w0, w1;
          asm("v_cvt_pk_bf16_f32 %0, %1, %2" : "=v"(w0) : "v"(sv[kb*4+0]), "v"(sv[kb*4+1]));
          asm("v_cvt_pk_bf16_f32 %0, %1, %2" : "=v"(w1) : "v"(sv[kb*4+2]), "v"(sv[kb*4+3]));
          uint32_t* dst = (uint32_t*)&P_lds[wave][lq * 72 + kb * 16 + lg * 4];
          dst[0] = w0; dst[1] = w1;
        }
        short8 pa0 = *(const short8*)(&P_lds[wave][lq * 72 + lg * 8]);
        short8 pa1 = *(const short8*)(&P_lds[wave][lq * 72 + 32 + lg * 8]);

        __builtin_amdgcn_s_setprio(1);
        #pragma unroll
        for (int nb = 0; nb < 4; ++nb) {
          o_acc[nb] = __builtin_amdgcn_mfma_f32_16x16x32_bf16(pa0, vb[nb][0], o_acc[nb], 0, 0, 0);
          o_acc[nb] = __builtin_amdgcn_mfma_f32_16x16x32_bf16(pa1, vb[nb][1], o_acc[nb], 0, 0, 0);
        }
        __builtin_amdgcn_s_setprio(0);
      }
    }
    asm volatile("s_barrier" ::: "memory");
  }

  #pragma unroll
  for (int i = 0; i < 4; ++i) {
    const float rl = 1.0f / __shfl(l_run, lg * 4 + i);
    const int row = q0w + lg * 4 + i;
    #pragma unroll
    for (int nb = 0; nb < 4; ++nb) {
      const int col = h * 64 + nb * 16 + lq;
      vw[((size_t)b * NS + row) * ND + col] = f2bf(o_acc[nb][i] * rl);
    }
  }
}

// ---------------- LN1 (bf16 split-K out-proj partials): n = LN(x + p0 + p1 + bvw) ----------------
__global__ __launch_bounds__(256)
void k_add_ln1s(const float* __restrict__ X, const u16* __restrict__ P0,
                const u16* __restrict__ P1, const float* __restrict__ bias,
                const float* __restrict__ g, const float* __restrict__ beta,
                float* __restrict__ outf, u16* __restrict__ outb)
{
  const int row = blockIdx.x;
  const int t = threadIdx.x;
  const size_t base = (size_t)row * ND;
  float4 u  = ((const float4*)(X + base))[t];
  uint2 a0 = ((const uint2*)(P0 + base))[t];
  uint2 a1 = ((const uint2*)(P1 + base))[t];
  float4 bv = ((const float4*)bias)[t];
  float x0 = u.x + bv.x + bf2f((u16)(a0.x)) + bf2f((u16)(a1.x));
  float x1 = u.y + bv.y + bf2f((u16)(a0.x >> 16)) + bf2f((u16)(a1.x >> 16));
  float x2 = u.z + bv.z + bf2f((u16)(a0.y)) + bf2f((u16)(a1.y));
  float x3 = u.w + bv.w + bf2f((u16)(a0.y >> 16)) + bf2f((u16)(a1.y >> 16));
  float s1 = x0 + x1 + x2 + x3;
  float s2 = x0*x0 + x1*x1 + x2*x2 + x3*x3;
  #pragma unroll
  for (int m = 32; m; m >>= 1) { s1 += __shfl_xor(s1, m); s2 += __shfl_xor(s2, m); }
  __shared__ float rs1[4], rs2[4];
  const int wave = t >> 6;
  if ((t & 63) == 0) { rs1[wave] = s1; rs2[wave] = s2; }
  __syncthreads();
  s1 = rs1[0] + rs1[1] + rs1[2] + rs1[3];
  s2 = rs2[0] + rs2[1] + rs2[2] + rs2[3];
  const float mean = s1 * (1.f / ND);
  const float var  = s2 * (1.f / ND) - mean * mean;
  const float rstd = rsqrtf(var + 1e-5f);
  float4 gg = ((const float4*)g)[t];
  float4 bb = ((const float4*)beta)[t];
  float y0 = gg.x * (x0 - mean) * rstd + bb.x;
  float y1 = gg.y * (x1 - mean) * rstd + bb.y;
  float y2 = gg.z * (x2 - mean) * rstd + bb.z;
  float y3 = gg.w * (x3 - mean) * rstd + bb.w;
  ((float4*)(outf + base))[t] = make_float4(y0, y1, y2, y3);
  uint2 ob;
  ob.x = (uint32_t)f2bf(y0) | ((uint32_t)f2bf(y1) << 16);
  ob.y = (uint32_t)f2bf(y2) | ((uint32_t)f2bf(y3) << 16);
  ((uint2*)(outb + base))[t] = ob;
}

// ---------------- LN2 (4 bf16 partials): h = LN(U + P0+P1+P2+P3 + bias) ----------------
__global__ __launch_bounds__(256)
void k_add_ln2b(const float* __restrict__ U,
                const u16* __restrict__ p0, const u16* __restrict__ p1,
                const u16* __restrict__ p2, const u16* __restrict__ p3,
                const float* __restrict__ bias,
                const float* __restrict__ g, const float* __restrict__ beta,
                float* __restrict__ outf)
{
  const int row = blockIdx.x;
  const int t = threadIdx.x;
  const size_t base = (size_t)row * ND;
  float4 u  = ((const float4*)(U + base))[t];
  float4 bv = ((const float4*)bias)[t];
  uint2 a0 = ((const uint2*)(p0 + base))[t];
  uint2 a1 = ((const uint2*)(p1 + base))[t];
  uint2 a2 = ((const uint2*)(p2 + base))[t];
  uint2 a3 = ((const uint2*)(p3 + base))[t];
  float x0 = u.x + bv.x + bf2f((u16)(a0.x)) + bf2f((u16)(a1.x)) + bf2f((u16)(a2.x)) + bf2f((u16)(a3.x));
  float x1 = u.y + bv.y + bf2f((u16)(a0.x >> 16)) + bf2f((u16)(a1.x >> 16)) + bf2f((u16)(a2.x >> 16)) + bf2f((u16)(a3.x >> 16));
  float x2 = u.z + bv.z + bf2f((u16)(a0.y)) + bf2f((u16)(a1.y)) + bf2f((u16)(a2.y)) + bf2f((u16)(a3.y));
  float x3 = u.w + bv.w + bf2f((u16)(a0.y >> 16)) + bf2f((u16)(a1.y >> 16)) + bf2f((u16)(a2.y >> 16)) + bf2f((u16)(a3.y >> 16));
  float s1 = x0 + x1 + x2 + x3;
  float s2 = x0*x0 + x1*x1 + x2*x2 + x3*x3;
  #pragma unroll
  for (int m = 32; m; m >>= 1) { s1 += __shfl_xor(s1, m); s2 += __shfl_xor(s2, m); }
  __shared__ float rs1[4], rs2[4];
  const int wave = t >> 6;
  if ((t & 63) == 0) { rs1[wave] = s1; rs2[wave] = s2; }
  __syncthreads();
  s1 = rs1[0] + rs1[1] + rs1[2] + rs1[3];
  s2 = rs2[0] + rs2[1] + rs2[2] + rs2[3];
  const float mean = s1 * (1.f / ND);
  const float var  = s2 * (1.f / ND) - mean * mean;
  const float rstd = rsqrtf(var + 1e-5f);
  float4 gg = ((const float4*)g)[t];
  float4 bb = ((const float4*)beta)[t];
  float y0 = gg.x * (x0 - mean) * rstd + bb.x;
  float y1 = gg.y * (x1 - mean) * rstd + bb.y;
  float y2 = gg.z * (x2 - mean) * rstd + bb.z;
  float y3 = gg.w * (x3 - mean) * rstd + bb.w;
  ((float4*)(outf + base))[t] = make_float4(y0, y1, y2, y3);
}

extern "C" void kernel_launch(void* const* d_in, const int* in_sizes, int n_in,
                              void* d_out, int out_size, void* d_ws, size_t ws_size,
                              hipStream_t stream) {
  const float* x    = (const float*)d_in[0];
  const float* Wqkv = (const float*)d_in[2];
  const float* bqkv = (const float*)d_in[3];
  const float* Wvw  = (const float*)d_in[4];
  const float* bvw  = (const float*)d_in[5];
  const float* g1   = (const float*)d_in[6];
  const float* b1   = (const float*)d_in[7];
  const float* WA   = (const float*)d_in[8];
  const float* bA   = (const float*)d_in[9];
  const float* WB   = (const float*)d_in[10];
  const float* bB   = (const float*)d_in[11];
  const float* g2   = (const float*)d_in[12];
  const float* b2   = (const float*)d_in[13];
  float* out = (float*)d_out;

  if (ws_size < 100663296) return;
  char* ws = (char*)d_ws;
  u16*  WqkvT = (u16*)(ws + 0);          // [3072][1024] bf16 (dead after QKV)
  u16*  WvwT  = (u16*)(ws + 6291456);    // (dead after out-proj)
  u16*  WAT   = (u16*)(ws + 8388608);    // (dead after MLP-A)
  u16*  WBT   = (u16*)(ws + 16777216);   // [1024][4096]
  u16*  xb    = (u16*)(ws + 25165824);   // [4096][1024] bf16
  u16*  qkvb  = (u16*)(ws + 33554432);   // [4096][3072] bf16
  u16*  vwb   = (u16*)(ws + 58720256);   // [4096][1024] bf16
  u16*  po0   = (u16*)(ws + 67108864);   // out-proj bf16 partial 0 (8MB)
  u16*  po1   = (u16*)(ws + 75497472);   // out-proj bf16 partial 1 (8MB)
  float* nf   = (float*)(ws + 83886080); // [4096][1024] f32
  u16*  nb    = (u16*)(ws + 25165824);   // alias xb (dead after QKV)
  u16*  z     = (u16*)(ws + 33554432);   // [4096][4096] bf16, alias qkvb+vwb
  u16*  Vtb   = (u16*)(ws + 67108864);   // alias po0/po1 (dead after attention)
  u16*  pb01  = (u16*)(ws + 0);          // MLP-B partials z=0 @0, z=1 @8MB
  u16*  pb23  = (u16*)(ws + 67108864);   // z=2 @64MB, z=3 @72MB (po dead after LN1)

  hipError_t e2 = hipFuncSetAttribute((const void*)&k_gemm256<true, true>,
                                      hipFuncAttributeMaxDynamicSharedMemorySize, 131072);
  hipError_t e1 = hipFuncSetAttribute((const void*)&k_gemm256<true, false>,
                                      hipFuncAttributeMaxDynamicSharedMemorySize, 131072);
  const bool use256 = (e1 == hipSuccess) && (e2 == hipSuccess);

  // 1. prep: weight transposes + x cast (one launch)
  k_prep<<<dim3(16384), 256, 0, stream>>>(x, xb, Wqkv, Wvw, WA, WB, WqkvT, WvwT, WAT, WBT);

  // 2. qkv = x @ Wqkv + bqkv -> bf16 [4096][3072]
  k_gemm_bt<true, false><<<dim3(3 * ND / 128, NBS / 128, 1), 256, 0, stream>>>(
      xb, WqkvT, bqkv, qkvb, NBS, 3 * ND, ND, ND, 0);

  // 3. V transpose, then flash attention (v8: QBLK=64, grid 1024, 3 blocks/CU)
  k_vt<<<dim3(NS / 64, NB * NH), 256, 0, stream>>>(qkvb, Vtb);
  k_flash_attn<<<dim3(NS / 64, NB * NH), 256, 0, stream>>>(qkvb, Vtb, vwb);

  // 4. out-proj split-K=2: bf16 partials -> po0, po1
  k_gemm_bt<true, false><<<dim3(ND / 128, NBS / 128, 2), 256, 0, stream>>>(
      vwb, WvwT, nullptr, po0, NBS, ND, ND, ND / 2, (size_t)(po1 - po0));

  // 5. n = LN(x + po0 + po1 + bvw) -> nf (f32) + nb (bf16)
  k_add_ln1s<<<dim3(NBS), 256, 0, stream>>>(x, po0, po1, bvw, g1, b1, nf, nb);

  // 6. z = relu(n @ WA + bA) -> bf16 [4096][4096]
  if (use256)
    k_gemm256<true, true><<<dim3(256), 512, 131072, stream>>>(
        nb, WAT, bA, z, NBS, 4 * ND, ND, ND, 16, 0, 0);
  else
    k_gemm_bt<true, true><<<dim3(4 * ND / 128, NBS / 128, 1), 256, 0, stream>>>(
        nb, WAT, bA, z, NBS, 4 * ND, ND, ND, 0);

  // 7+8. m = z @ WB (split-K=4 bf16 partials) ; h = LN(nf + Σp + bB)
  if (use256) {
    k_gemm256<true, false><<<dim3(64, 1, 4), 512, 131072, stream>>>(
        z, WBT, nullptr, pb01, NBS, ND, 4 * ND, ND, 4,
        (size_t)4194304, (size_t)(pb23 - pb01));
    k_add_ln2b<<<dim3(NBS), 256, 0, stream>>>(
        nf, pb01, pb01 + 4194304, pb23, pb23 + 4194304, bB, g2, b2, out);
  } else {
    // fallback: 4 chunks at linear stride from pb01 (0..32MB region is dead)
    k_gemm_bt<true, false><<<dim3(ND / 128, NBS / 128, 4), 256, 0, stream>>>(
        z, WBT, nullptr, pb01, NBS, ND, 4 * ND, ND, (size_t)4194304);
    k_add_ln2b<<<dim3(NBS), 256, 0, stream>>>(
        nf, pb01, pb01 + 4194304, pb01 + 2 * 4194304, pb01 + 3 * 4194304,
        bB, g2, b2, out);
  }
}

// Round 13
// 227.420 us; speedup vs baseline: 1.1068x; 1.1068x over previous
//
#include <hip/hip_runtime.h>
#include <stdint.h>

typedef unsigned short u16;
typedef __attribute__((ext_vector_type(8))) short short8;
typedef __attribute__((ext_vector_type(4))) short short4v;
typedef __attribute__((ext_vector_type(4))) float f32x4;

#define NB 2
#define NS 2048
#define ND 1024
#define NH 16
#define NDH 64
#define NBS (NB*NS)   // 4096 rows

__device__ __forceinline__ float bf2f(u16 u) {
  union { uint32_t i; float f; } c; c.i = ((uint32_t)u) << 16; return c.f;
}
__device__ __forceinline__ u16 f2bf(float f) {
  union { float f; uint32_t i; } c; c.f = f;
  uint32_t r = (c.i + 0x7fffu + ((c.i >> 16) & 1u)) >> 16;
  return (u16)r;
}

// ---------------- prep: 4 weight transposes + x->bf16 cast, ONE launch ----------------
__global__ __launch_bounds__(256)
void k_prep(const float* __restrict__ x, u16* __restrict__ xb,
            const float* __restrict__ Wqkv, const float* __restrict__ Wvw,
            const float* __restrict__ WA, const float* __restrict__ WB,
            u16* __restrict__ WqkvT, u16* __restrict__ WvwT,
            u16* __restrict__ WAT, u16* __restrict__ WBT) {
  __shared__ float tile[32][33];
  int id = blockIdx.x;
  if (id >= 12288) {           // cast blocks: 4096 x (256 thr x float4)
    int i = (id - 12288) * 256 + threadIdx.x;
    float4 v = ((const float4*)x)[i];
    uint2 o;
    o.x = (uint32_t)f2bf(v.x) | ((uint32_t)f2bf(v.y) << 16);
    o.y = (uint32_t)f2bf(v.z) | ((uint32_t)f2bf(v.w) << 16);
    ((uint2*)xb)[i] = o;
    return;
  }
  const float* W; u16* WT; int K, N, tid;
  if (id < 3072)      { W = Wqkv; WT = WqkvT; K = 1024; N = 3072; tid = id; }
  else if (id < 4096) { W = Wvw;  WT = WvwT;  K = 1024; N = 1024; tid = id - 3072; }
  else if (id < 8192) { W = WA;   WT = WAT;   K = 1024; N = 4096; tid = id - 4096; }
  else                { W = WB;   WT = WBT;   K = 4096; N = 1024; tid = id - 8192; }
  const int ntx = N >> 5;
  const int n0 = (tid % ntx) << 5, k0 = (tid / ntx) << 5;
  const int tx = threadIdx.x & 31, ty = threadIdx.x >> 5;
  #pragma unroll
  for (int j = 0; j < 4; ++j)
    tile[ty + 8*j][tx] = W[(size_t)(k0 + ty + 8*j) * N + (n0 + tx)];
  __syncthreads();
  const int r = threadIdx.x >> 3;
  const int c4 = (threadIdx.x & 7) * 4;
  short4v o;
  #pragma unroll
  for (int i = 0; i < 4; ++i) o[i] = (short)f2bf(tile[c4 + i][r]);
  *(short4v*)(WT + (size_t)(n0 + r) * K + k0 + c4) = o;
}

// ---------------- transpose V out of qkv: [z][dh] -> Vt[bh][dh][z] (bf16) ----------------
__global__ __launch_bounds__(256)
void k_vt(const u16* __restrict__ qkv, u16* __restrict__ Vt) {
  __shared__ u16 tile[64][72];
  const int zb = blockIdx.x;
  const int bh = blockIdx.y;
  const int b = bh >> 4, h = bh & 15;
  const int t = threadIdx.x;
  const int r = t >> 2, seg = (t & 3) * 16;
  const u16* src = qkv + ((size_t)(b * NS + zb * 64 + r)) * 3072 + 2048 + h * 64 + seg;
  *(short8*)(&tile[r][seg])     = *(const short8*)(src);
  *(short8*)(&tile[r][seg + 8]) = *(const short8*)(src + 8);
  __syncthreads();
  const int dh = t >> 2, zs = (t & 3) * 16;
  short8 o0, o1;
  #pragma unroll
  for (int i = 0; i < 8; ++i) o0[i] = (short)tile[zs + i][dh];
  #pragma unroll
  for (int i = 0; i < 8; ++i) o1[i] = (short)tile[zs + 8 + i][dh];
  u16* dst = Vt + (size_t)(bh * 64 + dh) * NS + zb * 64 + zs;
  *(short8*)(dst)     = o0;
  *(short8*)(dst + 8) = o1;
}

// ---------------- async global->LDS, 16B ----------------
__device__ __forceinline__ void gload_lds16(const void* g, void* l) {
  __builtin_amdgcn_global_load_lds(
      (const __attribute__((address_space(1))) void*)(void*)(uintptr_t)g,
      (__attribute__((address_space(3))) void*)l, 16, 0, 0);
}

// ---------------- 128x128 bf16 MFMA GEMM (m97 structure), split-K capable ----------------
template<bool OUT_BF16, bool RELU>
__global__ __launch_bounds__(256)
void k_gemm_bt(const u16* __restrict__ A, const u16* __restrict__ BT,
               const float* __restrict__ bias, void* __restrict__ C,
               int M, int N, int Kstride, int Klen, size_t zCstride)
{
  __shared__ u16 As[128 * 64];
  __shared__ u16 Bs[128 * 64];
  const int t = threadIdx.x, wave = t >> 6, lane = t & 63;
  const int m0 = blockIdx.y * 128, n0 = blockIdx.x * 128;
  const int wr = wave >> 1, wc = wave & 1;
  const int koff = blockIdx.z * Klen;
  A  += koff;
  BT += koff;

  f32x4 acc[4][4] = {};

  int srow[4], scol[4];
  #pragma unroll
  for (int p = 0; p < 4; ++p) {
    int o = p * 4096 + wave * 1024 + lane * 16;
    int r = o >> 7;
    int cb = o & 127;
    srow[p] = r;
    scol[p] = (cb ^ ((r & 7) << 4)) >> 1;
  }

  const int nkt = Klen >> 6;
  for (int kt = 0; kt < nkt; ++kt) {
    const int k0 = kt << 6;
    #pragma unroll
    for (int p = 0; p < 4; ++p) {
      const u16* srcA = A  + (size_t)(m0 + srow[p]) * Kstride + k0 + scol[p];
      const u16* srcB = BT + (size_t)(n0 + srow[p]) * Kstride + k0 + scol[p];
      gload_lds16(srcA, (char*)As + p * 4096 + wave * 1024);
      gload_lds16(srcB, (char*)Bs + p * 4096 + wave * 1024);
    }
    asm volatile("s_waitcnt vmcnt(0)" ::: "memory");
    __syncthreads();

    #pragma unroll
    for (int kk = 0; kk < 2; ++kk) {
      const int cbase = kk * 64 + ((lane >> 4) << 4);
      short8 af[4], bf[4];
      #pragma unroll
      for (int mi = 0; mi < 4; ++mi) {
        int r = wr * 64 + mi * 16 + (lane & 15);
        af[mi] = *(const short8*)((const char*)As + r * 128 + (cbase ^ ((r & 7) << 4)));
      }
      #pragma unroll
      for (int nj = 0; nj < 4; ++nj) {
        int r = wc * 64 + nj * 16 + (lane & 15);
        bf[nj] = *(const short8*)((const char*)Bs + r * 128 + (cbase ^ ((r & 7) << 4)));
      }
      #pragma unroll
      for (int mi = 0; mi < 4; ++mi)
        #pragma unroll
        for (int nj = 0; nj < 4; ++nj)
          acc[mi][nj] = __builtin_amdgcn_mfma_f32_16x16x32_bf16(af[mi], bf[nj], acc[mi][nj], 0, 0, 0);
    }
    __syncthreads();
  }

  const int lr = (lane >> 4) << 2;
  const int lc = lane & 15;
  #pragma unroll
  for (int nj = 0; nj < 4; ++nj) {
    const int col = n0 + wc * 64 + nj * 16 + lc;
    const float bs = bias ? bias[col] : 0.f;
    #pragma unroll
    for (int mi = 0; mi < 4; ++mi) {
      const int row = m0 + wr * 64 + mi * 16 + lr;
      #pragma unroll
      for (int i = 0; i < 4; ++i) {
        float v = acc[mi][nj][i] + bs;
        if (RELU) v = fmaxf(v, 0.f);
        if (OUT_BF16) ((u16*)C)[blockIdx.z * zCstride + (size_t)(row + i) * N + col] = f2bf(v);
        else          ((float*)C)[blockIdx.z * zCstride + (size_t)(row + i) * N + col] = v;
      }
    }
  }
}

// ---------------- 256x256 8-wave 8-PHASE pipelined GEMM ----------------
__device__ __forceinline__ short8 lds_frag8(const char* base, int row, int kkbyte) {
  return *(const short8*)(base + row * 128 + (kkbyte ^ ((row & 7) << 4)));
}

template<bool OUT_BF16, bool RELU>
__global__ __launch_bounds__(512, 2)
void k_gemm256(const u16* __restrict__ A, const u16* __restrict__ BT,
               const float* __restrict__ bias, void* __restrict__ C,
               int M, int N, int Kstride, int Klen, int nbx,
               size_t zs1, size_t zs2)
{
  extern __shared__ char lds[];
  char* ldsA = lds;
  char* ldsB = lds + 65536;
  const int t = threadIdx.x, wave = t >> 6, lane = t & 63;
  const int lg = lane >> 4, lq = lane & 15;
  const int wr = wave >> 2, wc = wave & 3;

  const int nwg = gridDim.x;
  const int sw = (blockIdx.x & 7) * (nwg >> 3) + (blockIdx.x >> 3);
  const int bx = sw % nbx, by = sw / nbx;
  const int m0 = by * 256, n0 = bx * 256;

  const int koff = blockIdx.z * Klen;
  A  += koff;
  BT += koff;

  const int rr = t >> 3;
  const int scol = ((t & 7) ^ ((t >> 3) & 7)) * 8;
  const u16* Asrc = A  + (size_t)(m0 + rr) * Kstride + scol;
  const u16* Bsrc = BT + (size_t)(n0 + rr) * Kstride + scol;

  const int nkt = Klen >> 6;
  const int nht = nkt << 2;

  f32x4 acc[8][4] = {};
  short8 af[4][2], bf[4][2];

  auto STAGE = [&](int s) {
    if (s < nht) {
      const int tile = s >> 2, part = s & 3, half = part & 1, slot = tile & 1;
      const u16* src = (part < 2 ? Bsrc : Asrc) + (size_t)(half * 128) * Kstride + tile * 64;
      char* d = (part < 2 ? ldsB : ldsA) + slot * 32768 + half * 16384 + wave * 1024;
      gload_lds16(src, d);
      gload_lds16(src + (size_t)64 * Kstride, d + 8192);
    }
  };
  auto RDA = [&](int slot, int mo) {
    const char* base = ldsA + slot * 32768;
    #pragma unroll
    for (int m = 0; m < 4; ++m) {
      const int row = wr * 128 + (mo + m) * 16 + lq;
      af[m][0] = lds_frag8(base, row, lg * 16);
      af[m][1] = lds_frag8(base, row, 64 + lg * 16);
    }
  };
  auto RDB = [&](int slot, int no) {
    const char* base = ldsB + slot * 32768;
    #pragma unroll
    for (int n = 0; n < 2; ++n) {
      const int row = wc * 64 + (no + n) * 16 + lq;
      bf[no + n][0] = lds_frag8(base, row, lg * 16);
      bf[no + n][1] = lds_frag8(base, row, 64 + lg * 16);
    }
  };
  auto MF = [&](int mo, int no) {
    __builtin_amdgcn_s_setprio(1);
    #pragma unroll
    for (int m = 0; m < 4; ++m)
      #pragma unroll
      for (int n = 0; n < 2; ++n) {
        acc[mo + m][no + n] = __builtin_amdgcn_mfma_f32_16x16x32_bf16(af[m][0], bf[no + n][0], acc[mo + m][no + n], 0, 0, 0);
        acc[mo + m][no + n] = __builtin_amdgcn_mfma_f32_16x16x32_bf16(af[m][1], bf[no + n][1], acc[mo + m][no + n], 0, 0, 0);
      }
    __builtin_amdgcn_s_setprio(0);
  };
  #define BAR() asm volatile("s_barrier" ::: "memory")

  #pragma unroll
  for (int s = 0; s < 6; ++s) STAGE(s);
  asm volatile("s_waitcnt vmcnt(4)" ::: "memory");
  __syncthreads();

  const int niter = nkt >> 1;
  #pragma unroll 1
  for (int i = 0; i < niter; ++i) {
    const int bs = 8 * i + 6;
    RDA(0, 0); RDB(0, 0); STAGE(bs + 0);
    BAR(); MF(0, 0); BAR();
    RDB(0, 2); STAGE(bs + 1);
    BAR(); MF(0, 2); BAR();
    RDA(0, 4); STAGE(bs + 2);
    BAR(); MF(4, 0); BAR();
    STAGE(bs + 3);
    if (i == niter - 1) { asm volatile("s_waitcnt vmcnt(0)" ::: "memory"); }
    else                { asm volatile("s_waitcnt vmcnt(4)" ::: "memory"); }
    BAR(); MF(4, 2); BAR();
    RDA(1, 0); RDB(1, 0); STAGE(bs + 4);
    BAR(); MF(0, 0); BAR();
    RDB(1, 2); STAGE(bs + 5);
    BAR(); MF(0, 2); BAR();
    RDA(1, 4); STAGE(bs + 6);
    BAR(); MF(4, 0); BAR();
    STAGE(bs + 7);
    asm volatile("s_waitcnt vmcnt(4)" ::: "memory");
    BAR(); MF(4, 2); BAR();
  }
  #undef BAR

  const size_t zoff = (size_t)(blockIdx.z & 1) * zs1 + (size_t)(blockIdx.z >> 1) * zs2;
  #pragma unroll
  for (int n = 0; n < 4; ++n) {
    const int col = n0 + wc * 64 + n * 16 + lq;
    const float bs = bias ? bias[col] : 0.f;
    #pragma unroll
    for (int m = 0; m < 8; ++m) {
      const int row = m0 + wr * 128 + m * 16 + lg * 4;
      #pragma unroll
      for (int i = 0; i < 4; ++i) {
        float v = acc[m][n][i] + bs;
        if (RELU) v = fmaxf(v, 0.f);
        if (OUT_BF16) ((u16*)C)[zoff + (size_t)(row + i) * N + col] = f2bf(v);
        else          ((float*)C)[zoff + (size_t)(row + i) * N + col] = v;
      }
    }
  }
}

// ---------------- flash attention v6 (proven best): QBLK=128, 8 waves, T14 reg-prefetch ----------------
__global__ __launch_bounds__(512)
void k_flash_attn(const u16* __restrict__ qkv, const u16* __restrict__ Vt,
                  u16* __restrict__ vw)
{
  __shared__ u16 Ks[2][64 * 64];
  __shared__ u16 Vts[2][64 * 64];
  __shared__ u16 P_lds[8][16 * 72];

  const int qb = 15 - (int)blockIdx.x;   // LPT
  const int bh = blockIdx.y;
  const int b = bh >> 4, h = bh & 15;
  const int t = threadIdx.x, wave = t >> 6, lane = t & 63;
  const int lg = lane >> 4, lq = lane & 15;

  const int q0w = qb * 128 + wave * 16;

  const float QSC = 0.18033688f;         // 0.125 * log2(e)
  short8 bq[2];
  {
    const u16* qrow = qkv + ((size_t)(b * NS + q0w + lq)) * 3072 + h * 64 + lg * 8;
    short8 r0 = *(const short8*)(qrow);
    short8 r1 = *(const short8*)(qrow + 32);
    union { short8 s; uint32_t u[4]; } o0, o1;
    #pragma unroll
    for (int p = 0; p < 4; ++p) {
      float a0 = bf2f((u16)r0[2*p]) * QSC, a1 = bf2f((u16)r0[2*p+1]) * QSC;
      float c0 = bf2f((u16)r1[2*p]) * QSC, c1 = bf2f((u16)r1[2*p+1]) * QSC;
      asm("v_cvt_pk_bf16_f32 %0, %1, %2" : "=v"(o0.u[p]) : "v"(a0), "v"(a1));
      asm("v_cvt_pk_bf16_f32 %0, %1, %2" : "=v"(o1.u[p]) : "v"(c0), "v"(c1));
    }
    bq[0] = o0.s; bq[1] = o1.s;
  }

  f32x4 o_acc[4] = {};
  float m_run = -1e30f, l_run = 0.f;

  const u16* kbase = qkv + (size_t)b * NS * 3072 + 1024 + h * 64;
  const u16* vtb   = Vt + (size_t)bh * 64 * NS;

  const int so = t * 16;
  const int sr = so >> 7;
  const int scb = (so & 127) ^ ((sr & 7) << 4);
  const int npairs = qb + 1;

  short8 rK0, rK1, rV0, rV1;
  auto LOADP = [&](int z0) {
    rK0 = *(const short8*)(kbase + (size_t)(z0 + sr) * 3072 + (scb >> 1));
    rK1 = *(const short8*)(kbase + (size_t)(z0 + 64 + sr) * 3072 + (scb >> 1));
    rV0 = *(const short8*)(vtb + (size_t)sr * NS + z0 + (scb >> 1));
    rV1 = *(const short8*)(vtb + (size_t)sr * NS + z0 + 64 + (scb >> 1));
  };

  LOADP(0);

  for (int kp = 0; kp < npairs; ++kp) {
    const int z0 = kp * 128;
    asm volatile("s_waitcnt vmcnt(0)" ::: "memory");
    *(short8*)((char*)Ks[0]  + so) = rK0;
    *(short8*)((char*)Ks[1]  + so) = rK1;
    *(short8*)((char*)Vts[0] + so) = rV0;
    *(short8*)((char*)Vts[1] + so) = rV1;
    if (kp + 1 < npairs) LOADP(z0 + 128);   // async: lands during compute below
    asm volatile("s_waitcnt lgkmcnt(0)" ::: "memory");  // ds_writes visible; vmcnt NOT drained
    asm volatile("s_barrier" ::: "memory");

    #pragma unroll
    for (int sub = 0; sub < 2; ++sub) {
      const int zz = z0 + (sub << 6);
      if (zz <= q0w + 15) {
        f32x4 s_acc[4];
        __builtin_amdgcn_s_setprio(1);
        #pragma unroll
        for (int kb = 0; kb < 4; ++kb) {
          const int r = kb * 16 + lq;
          const int sw = (r & 7) << 4;
          short8 ak0 = *(const short8*)((const char*)Ks[sub] + r * 128 + ((lg * 16) ^ sw));
          short8 ak1 = *(const short8*)((const char*)Ks[sub] + r * 128 + ((64 + lg * 16) ^ sw));
          f32x4 zr = {0.f, 0.f, 0.f, 0.f};
          zr = __builtin_amdgcn_mfma_f32_16x16x32_bf16(ak0, bq[0], zr, 0, 0, 0);
          s_acc[kb] = __builtin_amdgcn_mfma_f32_16x16x32_bf16(ak1, bq[1], zr, 0, 0, 0);
        }
        __builtin_amdgcn_s_setprio(0);

        // hoist V fragments: ds_read latency hides under softmax VALU
        short8 vb[4][2];
        #pragma unroll
        for (int nb = 0; nb < 4; ++nb) {
          const int rv = nb * 16 + lq;
          const int swv = (rv & 7) << 4;
          vb[nb][0] = *(const short8*)((const char*)Vts[sub] + rv * 128 + ((lg * 16) ^ swv));
          vb[nb][1] = *(const short8*)((const char*)Vts[sub] + rv * 128 + ((64 + lg * 16) ^ swv));
        }

        float sv[16];
        #pragma unroll
        for (int kb = 0; kb < 4; ++kb)
          #pragma unroll
          for (int i = 0; i < 4; ++i)
            sv[kb * 4 + i] = s_acc[kb][i];

        if (zz + 63 > q0w) {
          #pragma unroll
          for (int kb = 0; kb < 4; ++kb)
            #pragma unroll
            for (int i = 0; i < 4; ++i)
              if (zz + kb * 16 + lg * 4 + i > q0w + lq) sv[kb * 4 + i] = -1e30f;
        }

        float tm = -1e30f;
        #pragma unroll
        for (int j = 0; j < 16; ++j) tm = fmaxf(tm, sv[j]);
        tm = fmaxf(tm, __shfl_xor(tm, 16));
        tm = fmaxf(tm, __shfl_xor(tm, 32));

        if (!__all(tm <= m_run + 11.5415603f)) {
          const float m_new = fmaxf(m_run, tm);
          const float scl = __builtin_amdgcn_exp2f(m_run - m_new);
          float s0 = __shfl(scl, lg * 4 + 0);
          float s1 = __shfl(scl, lg * 4 + 1);
          float s2 = __shfl(scl, lg * 4 + 2);
          float s3 = __shfl(scl, lg * 4 + 3);
          #pragma unroll
          for (int nb = 0; nb < 4; ++nb) {
            o_acc[nb][0] *= s0; o_acc[nb][1] *= s1;
            o_acc[nb][2] *= s2; o_acc[nb][3] *= s3;
          }
          l_run *= scl;
          m_run = m_new;
        }

        float ts = 0.f;
        #pragma unroll
        for (int j = 0; j < 16; ++j) {
          float p = __builtin_amdgcn_exp2f(sv[j] - m_run);
          sv[j] = p; ts += p;
        }
        ts += __shfl_xor(ts, 16);
        ts += __shfl_xor(ts, 32);
        l_run += ts;

        #pragma unroll
        for (int kb = 0; kb < 4; ++kb) {
          uint32_t w0, w1;
          asm("v_cvt_pk_bf16_f32 %0, %1, %2" : "=v"(w0) : "v"(sv[kb*4+0]), "v"(sv[kb*4+1]));
          asm("v_cvt_pk_bf16_f32 %0, %1, %2" : "=v"(w1) : "v"(sv[kb*4+2]), "v"(sv[kb*4+3]));
          uint32_t* dst = (uint32_t*)&P_lds[wave][lq * 72 + kb * 16 + lg * 4];
          dst[0] = w0; dst[1] = w1;
        }
        short8 pa0 = *(const short8*)(&P_lds[wave][lq * 72 + lg * 8]);
        short8 pa1 = *(const short8*)(&P_lds[wave][lq * 72 + 32 + lg * 8]);

        __builtin_amdgcn_s_setprio(1);
        #pragma unroll
        for (int nb = 0; nb < 4; ++nb) {
          o_acc[nb] = __builtin_amdgcn_mfma_f32_16x16x32_bf16(pa0, vb[nb][0], o_acc[nb], 0, 0, 0);
          o_acc[nb] = __builtin_amdgcn_mfma_f32_16x16x32_bf16(pa1, vb[nb][1], o_acc[nb], 0, 0, 0);
        }
        __builtin_amdgcn_s_setprio(0);
      }
    }
    asm volatile("s_barrier" ::: "memory");
  }

  #pragma unroll
  for (int i = 0; i < 4; ++i) {
    const float rl = 1.0f / __shfl(l_run, lg * 4 + i);
    const int row = q0w + lg * 4 + i;
    #pragma unroll
    for (int nb = 0; nb < 4; ++nb) {
      const int col = h * 64 + nb * 16 + lq;
      vw[((size_t)b * NS + row) * ND + col] = f2bf(o_acc[nb][i] * rl);
    }
  }
}

// ---------------- LN1 (bf16 split-K out-proj partials): n = LN(x + p0 + p1 + bvw) ----------------
__global__ __launch_bounds__(256)
void k_add_ln1s(const float* __restrict__ X, const u16* __restrict__ P0,
                const u16* __restrict__ P1, const float* __restrict__ bias,
                const float* __restrict__ g, const float* __restrict__ beta,
                float* __restrict__ outf, u16* __restrict__ outb)
{
  const int row = blockIdx.x;
  const int t = threadIdx.x;
  const size_t base = (size_t)row * ND;
  float4 u  = ((const float4*)(X + base))[t];
  uint2 a0 = ((const uint2*)(P0 + base))[t];
  uint2 a1 = ((const uint2*)(P1 + base))[t];
  float4 bv = ((const float4*)bias)[t];
  float x0 = u.x + bv.x + bf2f((u16)(a0.x)) + bf2f((u16)(a1.x));
  float x1 = u.y + bv.y + bf2f((u16)(a0.x >> 16)) + bf2f((u16)(a1.x >> 16));
  float x2 = u.z + bv.z + bf2f((u16)(a0.y)) + bf2f((u16)(a1.y));
  float x3 = u.w + bv.w + bf2f((u16)(a0.y >> 16)) + bf2f((u16)(a1.y >> 16));
  float s1 = x0 + x1 + x2 + x3;
  float s2 = x0*x0 + x1*x1 + x2*x2 + x3*x3;
  #pragma unroll
  for (int m = 32; m; m >>= 1) { s1 += __shfl_xor(s1, m); s2 += __shfl_xor(s2, m); }
  __shared__ float rs1[4], rs2[4];
  const int wave = t >> 6;
  if ((t & 63) == 0) { rs1[wave] = s1; rs2[wave] = s2; }
  __syncthreads();
  s1 = rs1[0] + rs1[1] + rs1[2] + rs1[3];
  s2 = rs2[0] + rs2[1] + rs2[2] + rs2[3];
  const float mean = s1 * (1.f / ND);
  const float var  = s2 * (1.f / ND) - mean * mean;
  const float rstd = rsqrtf(var + 1e-5f);
  float4 gg = ((const float4*)g)[t];
  float4 bb = ((const float4*)beta)[t];
  float y0 = gg.x * (x0 - mean) * rstd + bb.x;
  float y1 = gg.y * (x1 - mean) * rstd + bb.y;
  float y2 = gg.z * (x2 - mean) * rstd + bb.z;
  float y3 = gg.w * (x3 - mean) * rstd + bb.w;
  ((float4*)(outf + base))[t] = make_float4(y0, y1, y2, y3);
  uint2 ob;
  ob.x = (uint32_t)f2bf(y0) | ((uint32_t)f2bf(y1) << 16);
  ob.y = (uint32_t)f2bf(y2) | ((uint32_t)f2bf(y3) << 16);
  ((uint2*)(outb + base))[t] = ob;
}

// ---------------- LN2 (4 bf16 partials): h = LN(U + P0+P1+P2+P3 + bias) ----------------
__global__ __launch_bounds__(256)
void k_add_ln2b(const float* __restrict__ U,
                const u16* __restrict__ p0, const u16* __restrict__ p1,
                const u16* __restrict__ p2, const u16* __restrict__ p3,
                const float* __restrict__ bias,
                const float* __restrict__ g, const float* __restrict__ beta,
                float* __restrict__ outf)
{
  const int row = blockIdx.x;
  const int t = threadIdx.x;
  const size_t base = (size_t)row * ND;
  float4 u  = ((const float4*)(U + base))[t];
  float4 bv = ((const float4*)bias)[t];
  uint2 a0 = ((const uint2*)(p0 + base))[t];
  uint2 a1 = ((const uint2*)(p1 + base))[t];
  uint2 a2 = ((const uint2*)(p2 + base))[t];
  uint2 a3 = ((const uint2*)(p3 + base))[t];
  float x0 = u.x + bv.x + bf2f((u16)(a0.x)) + bf2f((u16)(a1.x)) + bf2f((u16)(a2.x)) + bf2f((u16)(a3.x));
  float x1 = u.y + bv.y + bf2f((u16)(a0.x >> 16)) + bf2f((u16)(a1.x >> 16)) + bf2f((u16)(a2.x >> 16)) + bf2f((u16)(a3.x >> 16));
  float x2 = u.z + bv.z + bf2f((u16)(a0.y)) + bf2f((u16)(a1.y)) + bf2f((u16)(a2.y)) + bf2f((u16)(a3.y));
  float x3 = u.w + bv.w + bf2f((u16)(a0.y >> 16)) + bf2f((u16)(a1.y >> 16)) + bf2f((u16)(a2.y >> 16)) + bf2f((u16)(a3.y >> 16));
  float s1 = x0 + x1 + x2 + x3;
  float s2 = x0*x0 + x1*x1 + x2*x2 + x3*x3;
  #pragma unroll
  for (int m = 32; m; m >>= 1) { s1 += __shfl_xor(s1, m); s2 += __shfl_xor(s2, m); }
  __shared__ float rs1[4], rs2[4];
  const int wave = t >> 6;
  if ((t & 63) == 0) { rs1[wave] = s1; rs2[wave] = s2; }
  __syncthreads();
  s1 = rs1[0] + rs1[1] + rs1[2] + rs1[3];
  s2 = rs2[0] + rs2[1] + rs2[2] + rs2[3];
  const float mean = s1 * (1.f / ND);
  const float var  = s2 * (1.f / ND) - mean * mean;
  const float rstd = rsqrtf(var + 1e-5f);
  float4 gg = ((const float4*)g)[t];
  float4 bb = ((const float4*)beta)[t];
  float y0 = gg.x * (x0 - mean) * rstd + bb.x;
  float y1 = gg.y * (x1 - mean) * rstd + bb.y;
  float y2 = gg.z * (x2 - mean) * rstd + bb.z;
  float y3 = gg.w * (x3 - mean) * rstd + bb.w;
  ((float4*)(outf + base))[t] = make_float4(y0, y1, y2, y3);
}

extern "C" void kernel_launch(void* const* d_in, const int* in_sizes, int n_in,
                              void* d_out, int out_size, void* d_ws, size_t ws_size,
                              hipStream_t stream) {
  const float* x    = (const float*)d_in[0];
  const float* Wqkv = (const float*)d_in[2];
  const float* bqkv = (const float*)d_in[3];
  const float* Wvw  = (const float*)d_in[4];
  const float* bvw  = (const float*)d_in[5];
  const float* g1   = (const float*)d_in[6];
  const float* b1   = (const float*)d_in[7];
  const float* WA   = (const float*)d_in[8];
  const float* bA   = (const float*)d_in[9];
  const float* WB   = (const float*)d_in[10];
  const float* bB   = (const float*)d_in[11];
  const float* g2   = (const float*)d_in[12];
  const float* b2   = (const float*)d_in[13];
  float* out = (float*)d_out;

  if (ws_size < 100663296) return;
  char* ws = (char*)d_ws;
  u16*  WqkvT = (u16*)(ws + 0);          // [3072][1024] bf16 (dead after QKV)
  u16*  WvwT  = (u16*)(ws + 6291456);    // (dead after out-proj)
  u16*  WAT   = (u16*)(ws + 8388608);    // (dead after MLP-A)
  u16*  WBT   = (u16*)(ws + 16777216);   // [1024][4096]
  u16*  xb    = (u16*)(ws + 25165824);   // [4096][1024] bf16
  u16*  qkvb  = (u16*)(ws + 33554432);   // [4096][3072] bf16
  u16*  vwb   = (u16*)(ws + 58720256);   // [4096][1024] bf16
  u16*  po0   = (u16*)(ws + 67108864);   // out-proj bf16 partial 0 (8MB)
  u16*  po1   = (u16*)(ws + 75497472);   // out-proj bf16 partial 1 (8MB)
  float* nf   = (float*)(ws + 83886080); // [4096][1024] f32
  u16*  nb    = (u16*)(ws + 25165824);   // alias xb (dead after QKV)
  u16*  z     = (u16*)(ws + 33554432);   // [4096][4096] bf16, alias qkvb+vwb
  u16*  Vtb   = (u16*)(ws + 67108864);   // alias po0/po1 (dead after attention)
  u16*  pb01  = (u16*)(ws + 0);          // MLP-B partials z=0 @0, z=1 @8MB
  u16*  pb23  = (u16*)(ws + 67108864);   // z=2 @64MB, z=3 @72MB (po dead after LN1)

  hipError_t e2 = hipFuncSetAttribute((const void*)&k_gemm256<true, true>,
                                      hipFuncAttributeMaxDynamicSharedMemorySize, 131072);
  hipError_t e1 = hipFuncSetAttribute((const void*)&k_gemm256<true, false>,
                                      hipFuncAttributeMaxDynamicSharedMemorySize, 131072);
  const bool use256 = (e1 == hipSuccess) && (e2 == hipSuccess);

  // 1. prep: weight transposes + x cast (one launch)
  k_prep<<<dim3(16384), 256, 0, stream>>>(x, xb, Wqkv, Wvw, WA, WB, WqkvT, WvwT, WAT, WBT);

  // 2. qkv = x @ Wqkv + bqkv -> bf16 [4096][3072]
  k_gemm_bt<true, false><<<dim3(3 * ND / 128, NBS / 128, 1), 256, 0, stream>>>(
      xb, WqkvT, bqkv, qkvb, NBS, 3 * ND, ND, ND, 0);

  // 3. V transpose, then flash attention (v6: QBLK=128, 8 waves)
  k_vt<<<dim3(NS / 64, NB * NH), 256, 0, stream>>>(qkvb, Vtb);
  k_flash_attn<<<dim3(NS / 128, NB * NH), 512, 0, stream>>>(qkvb, Vtb, vwb);

  // 4. out-proj split-K=2: bf16 partials -> po0, po1
  k_gemm_bt<true, false><<<dim3(ND / 128, NBS / 128, 2), 256, 0, stream>>>(
      vwb, WvwT, nullptr, po0, NBS, ND, ND, ND / 2, (size_t)(po1 - po0));

  // 5. n = LN(x + po0 + po1 + bvw) -> nf (f32) + nb (bf16)
  k_add_ln1s<<<dim3(NBS), 256, 0, stream>>>(x, po0, po1, bvw, g1, b1, nf, nb);

  // 6. z = relu(n @ WA + bA) -> bf16 [4096][4096]
  if (use256)
    k_gemm256<true, true><<<dim3(256), 512, 131072, stream>>>(
        nb, WAT, bA, z, NBS, 4 * ND, ND, ND, 16, 0, 0);
  else
    k_gemm_bt<true, true><<<dim3(4 * ND / 128, NBS / 128, 1), 256, 0, stream>>>(
        nb, WAT, bA, z, NBS, 4 * ND, ND, ND, 0);

  // 7+8. m = z @ WB (split-K=4 bf16 partials) ; h = LN(nf + Σp + bB)
  if (use256) {
    k_gemm256<true, false><<<dim3(64, 1, 4), 512, 131072, stream>>>(
        z, WBT, nullptr, pb01, NBS, ND, 4 * ND, ND, 4,
        (size_t)4194304, (size_t)(pb23 - pb01));
    k_add_ln2b<<<dim3(NBS), 256, 0, stream>>>(
        nf, pb01, pb01 + 4194304, pb23, pb23 + 4194304, bB, g2, b2, out);
  } else {
    k_gemm_bt<true, false><<<dim3(ND / 128, NBS / 128, 4), 256, 0, stream>>>(
        z, WBT, nullptr, pb01, NBS, ND, 4 * ND, ND, (size_t)4194304);
    k_add_ln2b<<<dim3(NBS), 256, 0, stream>>>(
        nf, pb01, pb01 + 4194304, pb01 + 2 * 4194304, pb01 + 3 * 4194304,
        bB, g2, b2, out);
  }
}

// Round 14
// 210.579 us; speedup vs baseline: 1.1953x; 1.0800x over previous
//
#include <hip/hip_runtime.h>
#include <stdint.h>

typedef unsigned short u16;
typedef __attribute__((ext_vector_type(8))) short short8;
typedef __attribute__((ext_vector_type(4))) short short4v;
typedef __attribute__((ext_vector_type(4))) float f32x4;

#define NB 2
#define NS 2048
#define ND 1024
#define NH 16
#define NDH 64
#define NBS (NB*NS)   // 4096 rows

__device__ __forceinline__ float bf2f(u16 u) {
  union { uint32_t i; float f; } c; c.i = ((uint32_t)u) << 16; return c.f;
}
__device__ __forceinline__ u16 f2bf(float f) {
  union { float f; uint32_t i; } c; c.f = f;
  uint32_t r = (c.i + 0x7fffu + ((c.i >> 16) & 1u)) >> 16;
  return (u16)r;
}

// ---------------- prep: 4 weight transposes + x->bf16 cast, ONE launch ----------------
__global__ __launch_bounds__(256)
void k_prep(const float* __restrict__ x, u16* __restrict__ xb,
            const float* __restrict__ Wqkv, const float* __restrict__ Wvw,
            const float* __restrict__ WA, const float* __restrict__ WB,
            u16* __restrict__ WqkvT, u16* __restrict__ WvwT,
            u16* __restrict__ WAT, u16* __restrict__ WBT) {
  __shared__ float tile[32][33];
  int id = blockIdx.x;
  if (id >= 12288) {           // cast blocks: 4096 x (256 thr x float4)
    int i = (id - 12288) * 256 + threadIdx.x;
    float4 v = ((const float4*)x)[i];
    uint2 o;
    o.x = (uint32_t)f2bf(v.x) | ((uint32_t)f2bf(v.y) << 16);
    o.y = (uint32_t)f2bf(v.z) | ((uint32_t)f2bf(v.w) << 16);
    ((uint2*)xb)[i] = o;
    return;
  }
  const float* W; u16* WT; int K, N, tid;
  if (id < 3072)      { W = Wqkv; WT = WqkvT; K = 1024; N = 3072; tid = id; }
  else if (id < 4096) { W = Wvw;  WT = WvwT;  K = 1024; N = 1024; tid = id - 3072; }
  else if (id < 8192) { W = WA;   WT = WAT;   K = 1024; N = 4096; tid = id - 4096; }
  else                { W = WB;   WT = WBT;   K = 4096; N = 1024; tid = id - 8192; }
  const int ntx = N >> 5;
  const int n0 = (tid % ntx) << 5, k0 = (tid / ntx) << 5;
  const int tx = threadIdx.x & 31, ty = threadIdx.x >> 5;
  #pragma unroll
  for (int j = 0; j < 4; ++j)
    tile[ty + 8*j][tx] = W[(size_t)(k0 + ty + 8*j) * N + (n0 + tx)];
  __syncthreads();
  const int r = threadIdx.x >> 3;
  const int c4 = (threadIdx.x & 7) * 4;
  short4v o;
  #pragma unroll
  for (int i = 0; i < 4; ++i) o[i] = (short)f2bf(tile[c4 + i][r]);
  *(short4v*)(WT + (size_t)(n0 + r) * K + k0 + c4) = o;
}

// ---------------- transpose V out of qkv: [z][dh] -> Vt[bh][dh][z] (bf16) ----------------
__global__ __launch_bounds__(256)
void k_vt(const u16* __restrict__ qkv, u16* __restrict__ Vt) {
  __shared__ u16 tile[64][72];
  const int zb = blockIdx.x;
  const int bh = blockIdx.y;
  const int b = bh >> 4, h = bh & 15;
  const int t = threadIdx.x;
  const int r = t >> 2, seg = (t & 3) * 16;
  const u16* src = qkv + ((size_t)(b * NS + zb * 64 + r)) * 3072 + 2048 + h * 64 + seg;
  *(short8*)(&tile[r][seg])     = *(const short8*)(src);
  *(short8*)(&tile[r][seg + 8]) = *(const short8*)(src + 8);
  __syncthreads();
  const int dh = t >> 2, zs = (t & 3) * 16;
  short8 o0, o1;
  #pragma unroll
  for (int i = 0; i < 8; ++i) o0[i] = (short)tile[zs + i][dh];
  #pragma unroll
  for (int i = 0; i < 8; ++i) o1[i] = (short)tile[zs + 8 + i][dh];
  u16* dst = Vt + (size_t)(bh * 64 + dh) * NS + zb * 64 + zs;
  *(short8*)(dst)     = o0;
  *(short8*)(dst + 8) = o1;
}

// ---------------- async global->LDS, 16B ----------------
__device__ __forceinline__ void gload_lds16(const void* g, void* l) {
  __builtin_amdgcn_global_load_lds(
      (const __attribute__((address_space(1))) void*)(void*)(uintptr_t)g,
      (__attribute__((address_space(3))) void*)l, 16, 0, 0);
}

// ---------------- 128x128 bf16 MFMA GEMM (m97 structure), split-K capable ----------------
template<bool OUT_BF16, bool RELU>
__global__ __launch_bounds__(256)
void k_gemm_bt(const u16* __restrict__ A, const u16* __restrict__ BT,
               const float* __restrict__ bias, void* __restrict__ C,
               int M, int N, int Kstride, int Klen, size_t zCstride)
{
  __shared__ u16 As[128 * 64];
  __shared__ u16 Bs[128 * 64];
  const int t = threadIdx.x, wave = t >> 6, lane = t & 63;
  const int m0 = blockIdx.y * 128, n0 = blockIdx.x * 128;
  const int wr = wave >> 1, wc = wave & 1;
  const int koff = blockIdx.z * Klen;
  A  += koff;
  BT += koff;

  f32x4 acc[4][4] = {};

  int srow[4], scol[4];
  #pragma unroll
  for (int p = 0; p < 4; ++p) {
    int o = p * 4096 + wave * 1024 + lane * 16;
    int r = o >> 7;
    int cb = o & 127;
    srow[p] = r;
    scol[p] = (cb ^ ((r & 7) << 4)) >> 1;
  }

  const int nkt = Klen >> 6;
  for (int kt = 0; kt < nkt; ++kt) {
    const int k0 = kt << 6;
    #pragma unroll
    for (int p = 0; p < 4; ++p) {
      const u16* srcA = A  + (size_t)(m0 + srow[p]) * Kstride + k0 + scol[p];
      const u16* srcB = BT + (size_t)(n0 + srow[p]) * Kstride + k0 + scol[p];
      gload_lds16(srcA, (char*)As + p * 4096 + wave * 1024);
      gload_lds16(srcB, (char*)Bs + p * 4096 + wave * 1024);
    }
    asm volatile("s_waitcnt vmcnt(0)" ::: "memory");
    __syncthreads();

    #pragma unroll
    for (int kk = 0; kk < 2; ++kk) {
      const int cbase = kk * 64 + ((lane >> 4) << 4);
      short8 af[4], bf[4];
      #pragma unroll
      for (int mi = 0; mi < 4; ++mi) {
        int r = wr * 64 + mi * 16 + (lane & 15);
        af[mi] = *(const short8*)((const char*)As + r * 128 + (cbase ^ ((r & 7) << 4)));
      }
      #pragma unroll
      for (int nj = 0; nj < 4; ++nj) {
        int r = wc * 64 + nj * 16 + (lane & 15);
        bf[nj] = *(const short8*)((const char*)Bs + r * 128 + (cbase ^ ((r & 7) << 4)));
      }
      #pragma unroll
      for (int mi = 0; mi < 4; ++mi)
        #pragma unroll
        for (int nj = 0; nj < 4; ++nj)
          acc[mi][nj] = __builtin_amdgcn_mfma_f32_16x16x32_bf16(af[mi], bf[nj], acc[mi][nj], 0, 0, 0);
    }
    __syncthreads();
  }

  const int lr = (lane >> 4) << 2;
  const int lc = lane & 15;
  #pragma unroll
  for (int nj = 0; nj < 4; ++nj) {
    const int col = n0 + wc * 64 + nj * 16 + lc;
    const float bs = bias ? bias[col] : 0.f;
    #pragma unroll
    for (int mi = 0; mi < 4; ++mi) {
      const int row = m0 + wr * 64 + mi * 16 + lr;
      #pragma unroll
      for (int i = 0; i < 4; ++i) {
        float v = acc[mi][nj][i] + bs;
        if (RELU) v = fmaxf(v, 0.f);
        if (OUT_BF16) ((u16*)C)[blockIdx.z * zCstride + (size_t)(row + i) * N + col] = f2bf(v);
        else          ((float*)C)[blockIdx.z * zCstride + (size_t)(row + i) * N + col] = v;
      }
    }
  }
}

// ---------------- 256x256 8-wave 8-PHASE pipelined GEMM ----------------
__device__ __forceinline__ short8 lds_frag8(const char* base, int row, int kkbyte) {
  return *(const short8*)(base + row * 128 + (kkbyte ^ ((row & 7) << 4)));
}

template<bool OUT_BF16, bool RELU>
__global__ __launch_bounds__(512, 2)
void k_gemm256(const u16* __restrict__ A, const u16* __restrict__ BT,
               const float* __restrict__ bias, void* __restrict__ C,
               int M, int N, int Kstride, int Klen, int nbx,
               size_t zs1, size_t zs2)
{
  extern __shared__ char lds[];
  char* ldsA = lds;
  char* ldsB = lds + 65536;
  const int t = threadIdx.x, wave = t >> 6, lane = t & 63;
  const int lg = lane >> 4, lq = lane & 15;
  const int wr = wave >> 2, wc = wave & 3;

  const int nwg = gridDim.x;
  const int sw = (blockIdx.x & 7) * (nwg >> 3) + (blockIdx.x >> 3);
  const int bx = sw % nbx, by = sw / nbx;
  const int m0 = by * 256, n0 = bx * 256;

  const int koff = blockIdx.z * Klen;
  A  += koff;
  BT += koff;

  const int rr = t >> 3;
  const int scol = ((t & 7) ^ ((t >> 3) & 7)) * 8;
  const u16* Asrc = A  + (size_t)(m0 + rr) * Kstride + scol;
  const u16* Bsrc = BT + (size_t)(n0 + rr) * Kstride + scol;

  const int nkt = Klen >> 6;
  const int nht = nkt << 2;

  f32x4 acc[8][4] = {};
  short8 af[4][2], bf[4][2];

  auto STAGE = [&](int s) {
    if (s < nht) {
      const int tile = s >> 2, part = s & 3, half = part & 1, slot = tile & 1;
      const u16* src = (part < 2 ? Bsrc : Asrc) + (size_t)(half * 128) * Kstride + tile * 64;
      char* d = (part < 2 ? ldsB : ldsA) + slot * 32768 + half * 16384 + wave * 1024;
      gload_lds16(src, d);
      gload_lds16(src + (size_t)64 * Kstride, d + 8192);
    }
  };
  auto RDA = [&](int slot, int mo) {
    const char* base = ldsA + slot * 32768;
    #pragma unroll
    for (int m = 0; m < 4; ++m) {
      const int row = wr * 128 + (mo + m) * 16 + lq;
      af[m][0] = lds_frag8(base, row, lg * 16);
      af[m][1] = lds_frag8(base, row, 64 + lg * 16);
    }
  };
  auto RDB = [&](int slot, int no) {
    const char* base = ldsB + slot * 32768;
    #pragma unroll
    for (int n = 0; n < 2; ++n) {
      const int row = wc * 64 + (no + n) * 16 + lq;
      bf[no + n][0] = lds_frag8(base, row, lg * 16);
      bf[no + n][1] = lds_frag8(base, row, 64 + lg * 16);
    }
  };
  auto MF = [&](int mo, int no) {
    __builtin_amdgcn_s_setprio(1);
    #pragma unroll
    for (int m = 0; m < 4; ++m)
      #pragma unroll
      for (int n = 0; n < 2; ++n) {
        acc[mo + m][no + n] = __builtin_amdgcn_mfma_f32_16x16x32_bf16(af[m][0], bf[no + n][0], acc[mo + m][no + n], 0, 0, 0);
        acc[mo + m][no + n] = __builtin_amdgcn_mfma_f32_16x16x32_bf16(af[m][1], bf[no + n][1], acc[mo + m][no + n], 0, 0, 0);
      }
    __builtin_amdgcn_s_setprio(0);
  };
  #define BAR() asm volatile("s_barrier" ::: "memory")

  #pragma unroll
  for (int s = 0; s < 6; ++s) STAGE(s);
  asm volatile("s_waitcnt vmcnt(4)" ::: "memory");
  __syncthreads();

  const int niter = nkt >> 1;
  #pragma unroll 1
  for (int i = 0; i < niter; ++i) {
    const int bs = 8 * i + 6;
    RDA(0, 0); RDB(0, 0); STAGE(bs + 0);
    BAR(); MF(0, 0); BAR();
    RDB(0, 2); STAGE(bs + 1);
    BAR(); MF(0, 2); BAR();
    RDA(0, 4); STAGE(bs + 2);
    BAR(); MF(4, 0); BAR();
    STAGE(bs + 3);
    if (i == niter - 1) { asm volatile("s_waitcnt vmcnt(0)" ::: "memory"); }
    else                { asm volatile("s_waitcnt vmcnt(4)" ::: "memory"); }
    BAR(); MF(4, 2); BAR();
    RDA(1, 0); RDB(1, 0); STAGE(bs + 4);
    BAR(); MF(0, 0); BAR();
    RDB(1, 2); STAGE(bs + 5);
    BAR(); MF(0, 2); BAR();
    RDA(1, 4); STAGE(bs + 6);
    BAR(); MF(4, 0); BAR();
    STAGE(bs + 7);
    asm volatile("s_waitcnt vmcnt(4)" ::: "memory");
    BAR(); MF(4, 2); BAR();
  }
  #undef BAR

  const size_t zoff = (size_t)(blockIdx.z & 1) * zs1 + (size_t)(blockIdx.z >> 1) * zs2;
  #pragma unroll
  for (int n = 0; n < 4; ++n) {
    const int col = n0 + wc * 64 + n * 16 + lq;
    const float bs = bias ? bias[col] : 0.f;
    #pragma unroll
    for (int m = 0; m < 8; ++m) {
      const int row = m0 + wr * 128 + m * 16 + lg * 4;
      #pragma unroll
      for (int i = 0; i < 4; ++i) {
        float v = acc[m][n][i] + bs;
        if (RELU) v = fmaxf(v, 0.f);
        if (OUT_BF16) ((u16*)C)[zoff + (size_t)(row + i) * N + col] = f2bf(v);
        else          ((float*)C)[zoff + (size_t)(row + i) * N + col] = v;
      }
    }
  }
}

// ---------------- flash attention v9: v6 + complementary CU pairing ----------------
// Grid 512 linear. Block i and i+256 share a CU (round-robin dispatch), so pair
// qb=(15-j) with qb=j on the same CU: every CU gets exactly 17 pair-units of work.
__global__ __launch_bounds__(512)
void k_flash_attn(const u16* __restrict__ qkv, const u16* __restrict__ Vt,
                  u16* __restrict__ vw)
{
  __shared__ u16 Ks[2][64 * 64];
  __shared__ u16 Vts[2][64 * 64];
  __shared__ u16 P_lds[8][16 * 72];

  const int flat = blockIdx.x;          // 0..511
  const int half = flat >> 8;           // 0 or 1
  const int u    = flat & 255;
  const int j    = u >> 5;              // 0..7
  const int qb   = half ? j : 15 - j;   // half0: 15..8 (long), half1: 0..7 (short)
  const int bh   = u & 31;
  const int b = bh >> 4, h = bh & 15;
  const int t = threadIdx.x, wave = t >> 6, lane = t & 63;
  const int lg = lane >> 4, lq = lane & 15;

  const int q0w = qb * 128 + wave * 16;

  const float QSC = 0.18033688f;         // 0.125 * log2(e)
  short8 bq[2];
  {
    const u16* qrow = qkv + ((size_t)(b * NS + q0w + lq)) * 3072 + h * 64 + lg * 8;
    short8 r0 = *(const short8*)(qrow);
    short8 r1 = *(const short8*)(qrow + 32);
    union { short8 s; uint32_t u[4]; } o0, o1;
    #pragma unroll
    for (int p = 0; p < 4; ++p) {
      float a0 = bf2f((u16)r0[2*p]) * QSC, a1 = bf2f((u16)r0[2*p+1]) * QSC;
      float c0 = bf2f((u16)r1[2*p]) * QSC, c1 = bf2f((u16)r1[2*p+1]) * QSC;
      asm("v_cvt_pk_bf16_f32 %0, %1, %2" : "=v"(o0.u[p]) : "v"(a0), "v"(a1));
      asm("v_cvt_pk_bf16_f32 %0, %1, %2" : "=v"(o1.u[p]) : "v"(c0), "v"(c1));
    }
    bq[0] = o0.s; bq[1] = o1.s;
  }

  f32x4 o_acc[4] = {};
  float m_run = -1e30f, l_run = 0.f;

  const u16* kbase = qkv + (size_t)b * NS * 3072 + 1024 + h * 64;
  const u16* vtb   = Vt + (size_t)bh * 64 * NS;

  const int so = t * 16;
  const int sr = so >> 7;
  const int scb = (so & 127) ^ ((sr & 7) << 4);
  const int npairs = qb + 1;

  short8 rK0, rK1, rV0, rV1;
  auto LOADP = [&](int z0) {
    rK0 = *(const short8*)(kbase + (size_t)(z0 + sr) * 3072 + (scb >> 1));
    rK1 = *(const short8*)(kbase + (size_t)(z0 + 64 + sr) * 3072 + (scb >> 1));
    rV0 = *(const short8*)(vtb + (size_t)sr * NS + z0 + (scb >> 1));
    rV1 = *(const short8*)(vtb + (size_t)sr * NS + z0 + 64 + (scb >> 1));
  };

  LOADP(0);

  for (int kp = 0; kp < npairs; ++kp) {
    const int z0 = kp * 128;
    asm volatile("s_waitcnt vmcnt(0)" ::: "memory");
    *(short8*)((char*)Ks[0]  + so) = rK0;
    *(short8*)((char*)Ks[1]  + so) = rK1;
    *(short8*)((char*)Vts[0] + so) = rV0;
    *(short8*)((char*)Vts[1] + so) = rV1;
    if (kp + 1 < npairs) LOADP(z0 + 128);   // async: lands during compute below
    asm volatile("s_waitcnt lgkmcnt(0)" ::: "memory");  // ds_writes visible; vmcnt NOT drained
    asm volatile("s_barrier" ::: "memory");

    #pragma unroll
    for (int sub = 0; sub < 2; ++sub) {
      const int zz = z0 + (sub << 6);
      if (zz <= q0w + 15) {
        f32x4 s_acc[4];
        __builtin_amdgcn_s_setprio(1);
        #pragma unroll
        for (int kb = 0; kb < 4; ++kb) {
          const int r = kb * 16 + lq;
          const int sw = (r & 7) << 4;
          short8 ak0 = *(const short8*)((const char*)Ks[sub] + r * 128 + ((lg * 16) ^ sw));
          short8 ak1 = *(const short8*)((const char*)Ks[sub] + r * 128 + ((64 + lg * 16) ^ sw));
          f32x4 zr = {0.f, 0.f, 0.f, 0.f};
          zr = __builtin_amdgcn_mfma_f32_16x16x32_bf16(ak0, bq[0], zr, 0, 0, 0);
          s_acc[kb] = __builtin_amdgcn_mfma_f32_16x16x32_bf16(ak1, bq[1], zr, 0, 0, 0);
        }
        __builtin_amdgcn_s_setprio(0);

        // hoist V fragments: ds_read latency hides under softmax VALU
        short8 vb[4][2];
        #pragma unroll
        for (int nb = 0; nb < 4; ++nb) {
          const int rv = nb * 16 + lq;
          const int swv = (rv & 7) << 4;
          vb[nb][0] = *(const short8*)((const char*)Vts[sub] + rv * 128 + ((lg * 16) ^ swv));
          vb[nb][1] = *(const short8*)((const char*)Vts[sub] + rv * 128 + ((64 + lg * 16) ^ swv));
        }

        float sv[16];
        #pragma unroll
        for (int kb = 0; kb < 4; ++kb)
          #pragma unroll
          for (int i = 0; i < 4; ++i)
            sv[kb * 4 + i] = s_acc[kb][i];

        if (zz + 63 > q0w) {
          #pragma unroll
          for (int kb = 0; kb < 4; ++kb)
            #pragma unroll
            for (int i = 0; i < 4; ++i)
              if (zz + kb * 16 + lg * 4 + i > q0w + lq) sv[kb * 4 + i] = -1e30f;
        }

        float tm = -1e30f;
        #pragma unroll
        for (int j2 = 0; j2 < 16; ++j2) tm = fmaxf(tm, sv[j2]);
        tm = fmaxf(tm, __shfl_xor(tm, 16));
        tm = fmaxf(tm, __shfl_xor(tm, 32));

        if (!__all(tm <= m_run + 11.5415603f)) {
          const float m_new = fmaxf(m_run, tm);
          const float scl = __builtin_amdgcn_exp2f(m_run - m_new);
          float s0 = __shfl(scl, lg * 4 + 0);
          float s1 = __shfl(scl, lg * 4 + 1);
          float s2 = __shfl(scl, lg * 4 + 2);
          float s3 = __shfl(scl, lg * 4 + 3);
          #pragma unroll
          for (int nb = 0; nb < 4; ++nb) {
            o_acc[nb][0] *= s0; o_acc[nb][1] *= s1;
            o_acc[nb][2] *= s2; o_acc[nb][3] *= s3;
          }
          l_run *= scl;
          m_run = m_new;
        }

        float ts = 0.f;
        #pragma unroll
        for (int j2 = 0; j2 < 16; ++j2) {
          float p = __builtin_amdgcn_exp2f(sv[j2] - m_run);
          sv[j2] = p; ts += p;
        }
        ts += __shfl_xor(ts, 16);
        ts += __shfl_xor(ts, 32);
        l_run += ts;

        #pragma unroll
        for (int kb = 0; kb < 4; ++kb) {
          uint32_t w0, w1;
          asm("v_cvt_pk_bf16_f32 %0, %1, %2" : "=v"(w0) : "v"(sv[kb*4+0]), "v"(sv[kb*4+1]));
          asm("v_cvt_pk_bf16_f32 %0, %1, %2" : "=v"(w1) : "v"(sv[kb*4+2]), "v"(sv[kb*4+3]));
          uint32_t* dst = (uint32_t*)&P_lds[wave][lq * 72 + kb * 16 + lg * 4];
          dst[0] = w0; dst[1] = w1;
        }
        short8 pa0 = *(const short8*)(&P_lds[wave][lq * 72 + lg * 8]);
        short8 pa1 = *(const short8*)(&P_lds[wave][lq * 72 + 32 + lg * 8]);

        __builtin_amdgcn_s_setprio(1);
        #pragma unroll
        for (int nb = 0; nb < 4; ++nb) {
          o_acc[nb] = __builtin_amdgcn_mfma_f32_16x16x32_bf16(pa0, vb[nb][0], o_acc[nb], 0, 0, 0);
          o_acc[nb] = __builtin_amdgcn_mfma_f32_16x16x32_bf16(pa1, vb[nb][1], o_acc[nb], 0, 0, 0);
        }
        __builtin_amdgcn_s_setprio(0);
      }
    }
    asm volatile("s_barrier" ::: "memory");
  }

  #pragma unroll
  for (int i = 0; i < 4; ++i) {
    const float rl = 1.0f / __shfl(l_run, lg * 4 + i);
    const int row = q0w + lg * 4 + i;
    #pragma unroll
    for (int nb = 0; nb < 4; ++nb) {
      const int col = h * 64 + nb * 16 + lq;
      vw[((size_t)b * NS + row) * ND + col] = f2bf(o_acc[nb][i] * rl);
    }
  }
}

// ---------------- LN1 (bf16 split-K out-proj partials): n = LN(x + p0 + p1 + bvw) ----------------
__global__ __launch_bounds__(256)
void k_add_ln1s(const float* __restrict__ X, const u16* __restrict__ P0,
                const u16* __restrict__ P1, const float* __restrict__ bias,
                const float* __restrict__ g, const float* __restrict__ beta,
                float* __restrict__ outf, u16* __restrict__ outb)
{
  const int row = blockIdx.x;
  const int t = threadIdx.x;
  const size_t base = (size_t)row * ND;
  float4 u  = ((const float4*)(X + base))[t];
  uint2 a0 = ((const uint2*)(P0 + base))[t];
  uint2 a1 = ((const uint2*)(P1 + base))[t];
  float4 bv = ((const float4*)bias)[t];
  float x0 = u.x + bv.x + bf2f((u16)(a0.x)) + bf2f((u16)(a1.x));
  float x1 = u.y + bv.y + bf2f((u16)(a0.x >> 16)) + bf2f((u16)(a1.x >> 16));
  float x2 = u.z + bv.z + bf2f((u16)(a0.y)) + bf2f((u16)(a1.y));
  float x3 = u.w + bv.w + bf2f((u16)(a0.y >> 16)) + bf2f((u16)(a1.y >> 16));
  float s1 = x0 + x1 + x2 + x3;
  float s2 = x0*x0 + x1*x1 + x2*x2 + x3*x3;
  #pragma unroll
  for (int m = 32; m; m >>= 1) { s1 += __shfl_xor(s1, m); s2 += __shfl_xor(s2, m); }
  __shared__ float rs1[4], rs2[4];
  const int wave = t >> 6;
  if ((t & 63) == 0) { rs1[wave] = s1; rs2[wave] = s2; }
  __syncthreads();
  s1 = rs1[0] + rs1[1] + rs1[2] + rs1[3];
  s2 = rs2[0] + rs2[1] + rs2[2] + rs2[3];
  const float mean = s1 * (1.f / ND);
  const float var  = s2 * (1.f / ND) - mean * mean;
  const float rstd = rsqrtf(var + 1e-5f);
  float4 gg = ((const float4*)g)[t];
  float4 bb = ((const float4*)beta)[t];
  float y0 = gg.x * (x0 - mean) * rstd + bb.x;
  float y1 = gg.y * (x1 - mean) * rstd + bb.y;
  float y2 = gg.z * (x2 - mean) * rstd + bb.z;
  float y3 = gg.w * (x3 - mean) * rstd + bb.w;
  ((float4*)(outf + base))[t] = make_float4(y0, y1, y2, y3);
  uint2 ob;
  ob.x = (uint32_t)f2bf(y0) | ((uint32_t)f2bf(y1) << 16);
  ob.y = (uint32_t)f2bf(y2) | ((uint32_t)f2bf(y3) << 16);
  ((uint2*)(outb + base))[t] = ob;
}

// ---------------- LN2 (4 bf16 partials): h = LN(U + P0+P1+P2+P3 + bias) ----------------
__global__ __launch_bounds__(256)
void k_add_ln2b(const float* __restrict__ U,
                const u16* __restrict__ p0, const u16* __restrict__ p1,
                const u16* __restrict__ p2, const u16* __restrict__ p3,
                const float* __restrict__ bias,
                const float* __restrict__ g, const float* __restrict__ beta,
                float* __restrict__ outf)
{
  const int row = blockIdx.x;
  const int t = threadIdx.x;
  const size_t base = (size_t)row * ND;
  float4 u  = ((const float4*)(U + base))[t];
  float4 bv = ((const float4*)bias)[t];
  uint2 a0 = ((const uint2*)(p0 + base))[t];
  uint2 a1 = ((const uint2*)(p1 + base))[t];
  uint2 a2 = ((const uint2*)(p2 + base))[t];
  uint2 a3 = ((const uint2*)(p3 + base))[t];
  float x0 = u.x + bv.x + bf2f((u16)(a0.x)) + bf2f((u16)(a1.x)) + bf2f((u16)(a2.x)) + bf2f((u16)(a3.x));
  float x1 = u.y + bv.y + bf2f((u16)(a0.x >> 16)) + bf2f((u16)(a1.x >> 16)) + bf2f((u16)(a2.x >> 16)) + bf2f((u16)(a3.x >> 16));
  float x2 = u.z + bv.z + bf2f((u16)(a0.y)) + bf2f((u16)(a1.y)) + bf2f((u16)(a2.y)) + bf2f((u16)(a3.y));
  float x3 = u.w + bv.w + bf2f((u16)(a0.y >> 16)) + bf2f((u16)(a1.y >> 16)) + bf2f((u16)(a2.y >> 16)) + bf2f((u16)(a3.y >> 16));
  float s1 = x0 + x1 + x2 + x3;
  float s2 = x0*x0 + x1*x1 + x2*x2 + x3*x3;
  #pragma unroll
  for (int m = 32; m; m >>= 1) { s1 += __shfl_xor(s1, m); s2 += __shfl_xor(s2, m); }
  __shared__ float rs1[4], rs2[4];
  const int wave = t >> 6;
  if ((t & 63) == 0) { rs1[wave] = s1; rs2[wave] = s2; }
  __syncthreads();
  s1 = rs1[0] + rs1[1] + rs1[2] + rs1[3];
  s2 = rs2[0] + rs2[1] + rs2[2] + rs2[3];
  const float mean = s1 * (1.f / ND);
  const float var  = s2 * (1.f / ND) - mean * mean;
  const float rstd = rsqrtf(var + 1e-5f);
  float4 gg = ((const float4*)g)[t];
  float4 bb = ((const float4*)beta)[t];
  float y0 = gg.x * (x0 - mean) * rstd + bb.x;
  float y1 = gg.y * (x1 - mean) * rstd + bb.y;
  float y2 = gg.z * (x2 - mean) * rstd + bb.z;
  float y3 = gg.w * (x3 - mean) * rstd + bb.w;
  ((float4*)(outf + base))[t] = make_float4(y0, y1, y2, y3);
}

extern "C" void kernel_launch(void* const* d_in, const int* in_sizes, int n_in,
                              void* d_out, int out_size, void* d_ws, size_t ws_size,
                              hipStream_t stream) {
  const float* x    = (const float*)d_in[0];
  const float* Wqkv = (const float*)d_in[2];
  const float* bqkv = (const float*)d_in[3];
  const float* Wvw  = (const float*)d_in[4];
  const float* bvw  = (const float*)d_in[5];
  const float* g1   = (const float*)d_in[6];
  const float* b1   = (const float*)d_in[7];
  const float* WA   = (const float*)d_in[8];
  const float* bA   = (const float*)d_in[9];
  const float* WB   = (const float*)d_in[10];
  const float* bB   = (const float*)d_in[11];
  const float* g2   = (const float*)d_in[12];
  const float* b2   = (const float*)d_in[13];
  float* out = (float*)d_out;

  if (ws_size < 100663296) return;
  char* ws = (char*)d_ws;
  u16*  WqkvT = (u16*)(ws + 0);          // [3072][1024] bf16 (dead after QKV)
  u16*  WvwT  = (u16*)(ws + 6291456);    // (dead after out-proj)
  u16*  WAT   = (u16*)(ws + 8388608);    // (dead after MLP-A)
  u16*  WBT   = (u16*)(ws + 16777216);   // [1024][4096]
  u16*  xb    = (u16*)(ws + 25165824);   // [4096][1024] bf16
  u16*  qkvb  = (u16*)(ws + 33554432);   // [4096][3072] bf16
  u16*  vwb   = (u16*)(ws + 58720256);   // [4096][1024] bf16
  u16*  po0   = (u16*)(ws + 67108864);   // out-proj bf16 partial 0 (8MB)
  u16*  po1   = (u16*)(ws + 75497472);   // out-proj bf16 partial 1 (8MB)
  float* nf   = (float*)(ws + 83886080); // [4096][1024] f32
  u16*  nb    = (u16*)(ws + 25165824);   // alias xb (dead after QKV)
  u16*  z     = (u16*)(ws + 33554432);   // [4096][4096] bf16, alias qkvb+vwb
  u16*  Vtb   = (u16*)(ws + 67108864);   // alias po0/po1 (dead after attention)
  u16*  pb01  = (u16*)(ws + 0);          // MLP-B partials z=0 @0, z=1 @8MB
  u16*  pb23  = (u16*)(ws + 67108864);   // z=2 @64MB, z=3 @72MB (po dead after LN1)

  hipError_t e2 = hipFuncSetAttribute((const void*)&k_gemm256<true, true>,
                                      hipFuncAttributeMaxDynamicSharedMemorySize, 131072);
  hipError_t e1 = hipFuncSetAttribute((const void*)&k_gemm256<true, false>,
                                      hipFuncAttributeMaxDynamicSharedMemorySize, 131072);
  const bool use256 = (e1 == hipSuccess) && (e2 == hipSuccess);

  // 1. prep: weight transposes + x cast (one launch)
  k_prep<<<dim3(16384), 256, 0, stream>>>(x, xb, Wqkv, Wvw, WA, WB, WqkvT, WvwT, WAT, WBT);

  // 2. qkv = x @ Wqkv + bqkv -> bf16 [4096][3072]
  k_gemm_bt<true, false><<<dim3(3 * ND / 128, NBS / 128, 1), 256, 0, stream>>>(
      xb, WqkvT, bqkv, qkvb, NBS, 3 * ND, ND, ND, 0);

  // 3. V transpose, then flash attention (v9: complementary CU pairing, grid 512 linear)
  k_vt<<<dim3(NS / 64, NB * NH), 256, 0, stream>>>(qkvb, Vtb);
  k_flash_attn<<<dim3(512), 512, 0, stream>>>(qkvb, Vtb, vwb);

  // 4. out-proj split-K=2: bf16 partials -> po0, po1
  k_gemm_bt<true, false><<<dim3(ND / 128, NBS / 128, 2), 256, 0, stream>>>(
      vwb, WvwT, nullptr, po0, NBS, ND, ND, ND / 2, (size_t)(po1 - po0));

  // 5. n = LN(x + po0 + po1 + bvw) -> nf (f32) + nb (bf16)
  k_add_ln1s<<<dim3(NBS), 256, 0, stream>>>(x, po0, po1, bvw, g1, b1, nf, nb);

  // 6. z = relu(n @ WA + bA) -> bf16 [4096][4096]
  if (use256)
    k_gemm256<true, true><<<dim3(256), 512, 131072, stream>>>(
        nb, WAT, bA, z, NBS, 4 * ND, ND, ND, 16, 0, 0);
  else
    k_gemm_bt<true, true><<<dim3(4 * ND / 128, NBS / 128, 1), 256, 0, stream>>>(
        nb, WAT, bA, z, NBS, 4 * ND, ND, ND, 0);

  // 7+8. m = z @ WB (split-K=4 bf16 partials) ; h = LN(nf + Σp + bB)
  if (use256) {
    k_gemm256<true, false><<<dim3(64, 1, 4), 512, 131072, stream>>>(
        z, WBT, nullptr, pb01, NBS, ND, 4 * ND, ND, 4,
        (size_t)4194304, (size_t)(pb23 - pb01));
    k_add_ln2b<<<dim3(NBS), 256, 0, stream>>>(
        nf, pb01, pb01 + 4194304, pb23, pb23 + 4194304, bB, g2, b2, out);
  } else {
    k_gemm_bt<true, false><<<dim3(ND / 128, NBS / 128, 4), 256, 0, stream>>>(
        z, WBT, nullptr, pb01, NBS, ND, 4 * ND, ND, (size_t)4194304);
    k_add_ln2b<<<dim3(NBS), 256, 0, stream>>>(
        nf, pb01, pb01 + 4194304, pb01 + 2 * 4194304, pb01 + 3 * 4194304,
        bB, g2, b2, out);
  }
}